// Round 4
// baseline (1594.909 us; speedup 1.0000x reference)
//
#include <hip/hip_runtime.h>
#include <hip/hip_bf16.h>
#include <math.h>

typedef __bf16 bf16;
typedef __bf16 bf16x4 __attribute__((ext_vector_type(4)));
typedef __bf16 bf16x8 __attribute__((ext_vector_type(8)));
typedef float f32x4 __attribute__((ext_vector_type(4)));

#define GL_AS(p) ((const __attribute__((address_space(1))) void*)(p))
#define LDS_AS(p) ((__attribute__((address_space(3))) void*)(p))

// ---------------------------------------------------------------------------
// Bijective XCD-chunked remap (m204): hw round-robin -> contiguous chunk/XCD
// ---------------------------------------------------------------------------
__device__ inline void xcd_remap(int& bm, int& bn, int NBM, int NBN)
{
    const int nwg = NBM * NBN;
    const int flat = bm + NBM * bn;
    const int q = nwg >> 3, r = nwg & 7;
    const int x = flat & 7, i = flat >> 3;
    const int f2 = ((x < r) ? x * (q + 1) : r * (q + 1) + (x - r) * q) + i;
    bm = f2 % NBM;
    bn = f2 / NBM;
}

// ---------------------------------------------------------------------------
// Merged transpose + f32->bf16 cast for all 5 weight groups.
// Each 32x32 tile: in [R,C] f32 (z-batched) -> out [C,R] bf16.
// ---------------------------------------------------------------------------
struct TSeg {
    const float* in; bf16* out; int R, C, nTilesC, tilesPerZ, nTiles;
};

__global__ __launch_bounds__(256) void transpose_all_k(
    TSeg s0, TSeg s1, TSeg s2, TSeg s3, TSeg s4)
{
    int t = blockIdx.x;
    TSeg s;
    if (t < s0.nTiles) s = s0;
    else { t -= s0.nTiles;
    if (t < s1.nTiles) s = s1;
    else { t -= s1.nTiles;
    if (t < s2.nTiles) s = s2;
    else { t -= s2.nTiles;
    if (t < s3.nTiles) s = s3;
    else { t -= s3.nTiles; s = s4; }}}}

    const int z   = t / s.tilesPerZ;
    const int rem = t - z * s.tilesPerZ;
    const int cx  = rem % s.nTilesC, ry = rem / s.nTilesC;

    __shared__ float tl[32][33];
    const int c0 = cx * 32, r0 = ry * 32;
    const size_t zoff = (size_t)z * s.R * s.C;
    const float* inb = s.in + zoff;
    bf16* outb = s.out + zoff;
    const int tx = threadIdx.x, ty = threadIdx.y;   // (32, 8)
#pragma unroll
    for (int i = 0; i < 32; i += 8)
        tl[ty + i][tx] = inb[(size_t)(r0 + ty + i) * s.C + c0 + tx];
    __syncthreads();
#pragma unroll
    for (int i = 0; i < 32; i += 8)
        outb[(size_t)(c0 + ty + i) * s.R + r0 + tx] = (bf16)tl[tx][ty + i];
}

// ---------------------------------------------------------------------------
// Embedding + sinusoidal positional encoding -> x f32 [B*S, 1024]
// ---------------------------------------------------------------------------
__global__ __launch_bounds__(256) void embed_k(
    const int* __restrict__ tok, const float* __restrict__ emb,
    float* __restrict__ x)
{
    const int D = 1024;
    const int row = blockIdx.x;
    const int s = row & 1023;          // S = 1024
    const int t = tok[row];
    const int d0 = threadIdx.x * 4;
    const float c = 9.210340371976184f / 512.0f;
    const float div0 = expf(-(float)(d0 >> 1) * c);
    const float div1 = expf(-(float)((d0 >> 1) + 1) * c);
    const float a0 = (float)s * div0, a1 = (float)s * div1;
    const f32x4 e = *(const f32x4*)(emb + (size_t)t * D + d0);
    f32x4 o;
    o[0] = e[0] + sinf(a0);
    o[1] = e[1] + cosf(a0);
    o[2] = e[2] + sinf(a1);
    o[3] = e[3] + cosf(a1);
    *(f32x4*)(x + (size_t)row * D + d0) = o;
}

// ---------------------------------------------------------------------------
// LayerNorm (D=1024): x f32 -> out bf16, vectorized 4 elems/thread
// ---------------------------------------------------------------------------
__global__ __launch_bounds__(256) void layernorm_k(
    const float* __restrict__ x, const float* __restrict__ sc,
    const float* __restrict__ bi, bf16* __restrict__ out)
{
    const int D = 1024;
    const int row = blockIdx.x;
    const int d0 = threadIdx.x * 4;
    const f32x4 v = *(const f32x4*)(x + (size_t)row * D + d0);
    float s = v[0] + v[1] + v[2] + v[3];
    float q = v[0] * v[0] + v[1] * v[1] + v[2] * v[2] + v[3] * v[3];
#pragma unroll
    for (int o = 32; o; o >>= 1) { s += __shfl_xor(s, o); q += __shfl_xor(q, o); }
    __shared__ float ls[4], lq[4];
    const int w = threadIdx.x >> 6;
    if ((threadIdx.x & 63) == 0) { ls[w] = s; lq[w] = q; }
    __syncthreads();
    const float S = ls[0] + ls[1] + ls[2] + ls[3];
    const float Q = lq[0] + lq[1] + lq[2] + lq[3];
    const float mu = S * (1.0f / D);
    const float var = Q * (1.0f / D) - mu * mu;
    const float rstd = rsqrtf(var + 1e-5f);
    const f32x4 sc4 = *(const f32x4*)(sc + d0);
    const f32x4 bi4 = *(const f32x4*)(bi + d0);
    bf16x4 o4;
#pragma unroll
    for (int i = 0; i < 4; ++i) o4[i] = (bf16)((v[i] - mu) * rstd * sc4[i] + bi4[i]);
    *(bf16x4*)(out + (size_t)row * D + d0) = o4;
}

// ---------------------------------------------------------------------------
// GEMM: C[M,N] = A[M,K](bf16) @ Bt[N,K](bf16)^T, f32 accum, various epilogues
// 128x128 tile, BK=64, 4 waves (2x2), mfma_f32_16x16x32_bf16, XCD-swizzled
// EPI: 0 store bf16 | 1 Cf += acc (atomic if SK>1) | 2 bias+gelu->bf16
//      3 Cf += acc+bias (atomic if SK>1) | 4 Cf = acc+bias
//      5 qkv write: cols<2048 -> Cb, cols>=2048 -> Cb2 = vt[b][s/8][hd][8]
// SK: split-K factor (blockIdx.z = K-slice)
// ---------------------------------------------------------------------------
template <int EPI, int SK = 1>
__global__ __launch_bounds__(256, 2) void gemm_bt_k(
    const bf16* __restrict__ A, const bf16* __restrict__ Bt,
    float* __restrict__ Cf, bf16* __restrict__ Cb, bf16* __restrict__ Cb2,
    const float* __restrict__ bias, int M, int N, int K)
{
    __shared__ __align__(16) bf16 Al[128 * 64];
    __shared__ __align__(16) bf16 Bl[128 * 64];
    const int tid = threadIdx.x;
    const int l = tid & 63;
    const int wbase = tid & 192;                 // wave_id * 64
    const int wr = (tid >> 7) & 1, wc = (tid >> 6) & 1;
    int bm = blockIdx.x, bn = blockIdx.y;
    xcd_remap(bm, bn, gridDim.x, gridDim.y);
    const int kz = blockIdx.z;
    const int Kc = K / SK;                       // this slice's K extent

    f32x4 acc[4][4];
#pragma unroll
    for (int i = 0; i < 4; ++i)
#pragma unroll
        for (int j = 0; j < 4; ++j) acc[i][j] = (f32x4){0.f, 0.f, 0.f, 0.f};

    const bf16* Abase = A + (size_t)bm * 128 * K + (size_t)kz * Kc;
    const bf16* Bbase = Bt + (size_t)bn * 128 * K + (size_t)kz * Kc;

    for (int k0 = 0; k0 < Kc; k0 += 64) {
        // ---- stage A and B tiles: [128 rows][64 k] bf16, XOR-swizzled slots.
        // chunk c (16B): row=c>>3 slot=c&7; global col-block = slot ^ (row&7)
#pragma unroll
        for (int i = 0; i < 4; ++i) {
            const int c = i * 256 + tid;
            const int row = c >> 3, slot = c & 7;
            const int col = ((slot ^ (row & 7)) << 3);
            __builtin_amdgcn_global_load_lds(
                GL_AS(Abase + (size_t)row * K + k0 + col),
                LDS_AS(Al + (i * 256 + wbase) * 8), 16, 0, 0);
        }
#pragma unroll
        for (int i = 0; i < 4; ++i) {
            const int c = i * 256 + tid;
            const int row = c >> 3, slot = c & 7;
            const int col = ((slot ^ (row & 7)) << 3);
            __builtin_amdgcn_global_load_lds(
                GL_AS(Bbase + (size_t)row * K + k0 + col),
                LDS_AS(Bl + (i * 256 + wbase) * 8), 16, 0, 0);
        }
        __syncthreads();   // drains vmcnt: tiles visible

#pragma unroll
        for (int ks = 0; ks < 2; ++ks) {
            bf16x8 af[4], bfr[4];
            const int kb = ks * 64 + ((l >> 4) << 4);   // byte offset of lane's k-block
#pragma unroll
            for (int mi = 0; mi < 4; ++mi) {
                const int r = wr * 64 + mi * 16 + (l & 15);
                af[mi] = *(const bf16x8*)((const char*)Al + r * 128 + (kb ^ ((r & 7) << 4)));
            }
#pragma unroll
            for (int ni = 0; ni < 4; ++ni) {
                const int r = wc * 64 + ni * 16 + (l & 15);
                bfr[ni] = *(const bf16x8*)((const char*)Bl + r * 128 + (kb ^ ((r & 7) << 4)));
            }
#pragma unroll
            for (int mi = 0; mi < 4; ++mi)
#pragma unroll
                for (int ni = 0; ni < 4; ++ni)
                    acc[mi][ni] = __builtin_amdgcn_mfma_f32_16x16x32_bf16(
                        af[mi], bfr[ni], acc[mi][ni], 0, 0, 0);
        }
        __syncthreads();   // all reads done before next stage overwrites
    }

    // ---- epilogue: C/D layout col=lane&15, row=(lane>>4)*4+j  [m89/m91]
    const int colb = bn * 128 + wc * 64;
    const int rowb = bm * 128 + wr * 64 + ((l >> 4) << 2);
#pragma unroll
    for (int mi = 0; mi < 4; ++mi) {
#pragma unroll
        for (int ni = 0; ni < 4; ++ni) {
            const int col = colb + ni * 16 + (l & 15);
#pragma unroll
            for (int j = 0; j < 4; ++j) {
                const int row = rowb + mi * 16 + j;
                const float v = acc[mi][ni][j];
                if constexpr (EPI == 0) {
                    Cb[(size_t)row * N + col] = (bf16)v;
                } else if constexpr (EPI == 1) {
                    if constexpr (SK > 1) atomicAdd(&Cf[(size_t)row * N + col], v);
                    else                  Cf[(size_t)row * N + col] += v;
                } else if constexpr (EPI == 2) {
                    const float u = v + bias[col];
                    const float g = 0.5f * u * (1.0f + erff(u * 0.70710678118654752f));
                    Cb[(size_t)row * N + col] = (bf16)g;
                } else if constexpr (EPI == 3) {
                    const float add = (SK == 1 || kz == 0) ? v + bias[col] : v;
                    if constexpr (SK > 1) atomicAdd(&Cf[(size_t)row * N + col], add);
                    else                  Cf[(size_t)row * N + col] += add;
                } else if constexpr (EPI == 4) {
                    Cf[(size_t)row * N + col] = v + bias[col];
                } else {   // EPI == 5: qkv write; V cols -> s-blocked vt
                    if (col < 2048) {
                        Cb[(size_t)row * N + col] = (bf16)v;
                    } else {
                        // vt[b][s/8][hd][8]: chunk = row>>3 (incl. batch), lane j -> row&7
                        Cb2[((size_t)(row >> 3) * 1024 + (col - 2048)) * 8 + (row & 7)] = (bf16)v;
                    }
                }
            }
        }
    }
}

// ---------------------------------------------------------------------------
// MFMA flash attention v2. 4 waves per block, 64 q-rows per block (16/wave).
// K/V tiles (32 keys) staged cooperatively into double-buffered swizzled LDS,
// one tile ahead (global_load_lds overlaps compute; __syncthreads publishes).
// grid.x = B*H*(S/64) = 512.  qkv bf16 [B*S, 3072]: q at h*64+d, k at 1024+h*64+d.
// vt bf16 [b][s/8][1024 hd][8] (s-blocked, written by qkv GEMM).
// out o bf16 [B*S, 1024].
//
// Fragment conventions (proven by gemm_bt_k, m89/m91):
//   A-frag: lane l holds A[l&15][(l>>4)*8 + jj]   (8 contiguous k)
//   B-frag: lane l holds B[(l>>4)*8 + jj][l&15]
//   C:      lane l holds C[(l>>4)*4 + j][l&15]
// ---------------------------------------------------------------------------
__global__ __launch_bounds__(256) void attn_mfma_k(
    const bf16* __restrict__ qkv, const bf16* __restrict__ vt,
    bf16* __restrict__ o)
{
    // K tile: [32 kv-rows][64 d] bf16, 128 B/row, 8 slots of 16B, slot ^= (row&7)
    // V tile: [64 d-rows][32 s] bf16,  64 B/row, 4 slots of 16B, slot ^= (row>>1)&3
    __shared__ __align__(16) bf16 Kl[2][32 * 64];
    __shared__ __align__(16) bf16 Vl[2][64 * 32];
    __shared__ __align__(16) bf16 Pl[4][16][88];   // per-wave P round-trip

    const int tid = threadIdx.x;
    const int w = tid >> 6, l = tid & 63;
    const int g = l >> 4, lc = l & 15;
    const int qt = blockIdx.x & 15;      // S/64 = 16 q-blocks
    const int bh = blockIdx.x >> 4;
    const int h = bh & 15, b = bh >> 4;
    const int q0 = qt * 64;
    const int qw = q0 + w * 16;          // this wave's q-subtile
    const int diag = qw >> 5;            // wave's diagonal (masked) tile
    const int NT = (q0 >> 5) + 2;        // tiles staged by this block

    const bf16* qbase = qkv + (size_t)b * 1024 * 3072 + h * 64;
    const bf16* kbase = qbase + 1024;
    // vt: [b][s8][hd][8]; this head's hd base = h*64
    const bf16* vbase = vt + (size_t)b * 128 * 8192 + h * 64 * 8;

    // Q A-frags: lane holds Q[qw+lc][c*32 + g*8 + jj]
    bf16x8 af0, af1;
    {
        const bf16* qp = qbase + (size_t)(qw + lc) * 3072 + g * 8;
        af0 = *(const bf16x8*)qp;
        af1 = *(const bf16x8*)(qp + 32);
    }

    f32x4 acc[4];                        // O: rows qw+4g+j, cols dt*16+lc
#pragma unroll
    for (int dt = 0; dt < 4; ++dt) acc[dt] = (f32x4){0.f, 0.f, 0.f, 0.f};
    f32x4 m  = (f32x4){-1e30f, -1e30f, -1e30f, -1e30f};
    f32x4 ls = (f32x4){0.f, 0.f, 0.f, 0.f};   // lane-partial row sums

    // cooperative stage of tile t (256 threads, 1 chunk each per matrix)
    auto stage = [&](int t) {
        const int k0 = t * 32;
        const int buf = t & 1;
        {   // K: chunk=tid -> row=tid>>3, slot=tid&7; src d-octet = slot^(row&7)
            const int row = tid >> 3;
            const int d = (((tid & 7) ^ (row & 7)) << 3);
            __builtin_amdgcn_global_load_lds(
                GL_AS(kbase + (size_t)(k0 + row) * 3072 + d),
                LDS_AS(Kl[buf] + (tid & 192) * 8), 16, 0, 0);
        }
        {   // V: chunk=tid -> row=tid>>2 (hd), slot=tid&3; s-octet = slot^((row>>1)&3)
            const int row = tid >> 2;
            const int so = (tid & 3) ^ ((tid >> 3) & 3);
            __builtin_amdgcn_global_load_lds(
                GL_AS(vbase + (size_t)((k0 >> 3) + so) * 8192 + row * 8),
                LDS_AS(Vl[buf] + (tid & 192) * 8), 16, 0, 0);
        }
    };

    auto compute = [&](int t, bool MASKED) {
        const char* KT = (const char*)Kl[t & 1];
        const char* VT = (const char*)Vl[t & 1];
        const int k0 = t * 32;

        // K B-frags from LDS (swizzled): kfXY: X = key-half, Y = d-half
        const int r0 = lc, r1 = 16 + lc;
        const bf16x8 kf00 = *(const bf16x8*)(KT + r0 * 128 + 16 * (g       ^ (r0 & 7)));
        const bf16x8 kf01 = *(const bf16x8*)(KT + r0 * 128 + 16 * ((4 + g) ^ (r0 & 7)));
        const bf16x8 kf10 = *(const bf16x8*)(KT + r1 * 128 + 16 * (g       ^ (r1 & 7)));
        const bf16x8 kf11 = *(const bf16x8*)(KT + r1 * 128 + 16 * ((4 + g) ^ (r1 & 7)));

        f32x4 s0 = (f32x4){0.f, 0.f, 0.f, 0.f};
        f32x4 s1 = (f32x4){0.f, 0.f, 0.f, 0.f};
        s0 = __builtin_amdgcn_mfma_f32_16x16x32_bf16(af0, kf00, s0, 0, 0, 0);
        s0 = __builtin_amdgcn_mfma_f32_16x16x32_bf16(af1, kf01, s0, 0, 0, 0);
        s1 = __builtin_amdgcn_mfma_f32_16x16x32_bf16(af0, kf10, s1, 0, 0, 0);
        s1 = __builtin_amdgcn_mfma_f32_16x16x32_bf16(af1, kf11, s1, 0, 0, 0);

        // scale (+ causal mask on the diagonal tile)
#pragma unroll
        for (int j = 0; j < 4; ++j) {
            if (MASKED) {
                const int row = qw + 4 * g + j;
                s0[j] = (k0 + lc <= row)      ? s0[j] * 0.125f : -1e30f;
                s1[j] = (k0 + 16 + lc <= row) ? s1[j] * 0.125f : -1e30f;
            } else {
                s0[j] *= 0.125f;
                s1[j] *= 0.125f;
            }
        }

        // row-max across the 16 lanes of this group (cols) + both key-halves
        f32x4 tmx;
#pragma unroll
        for (int j = 0; j < 4; ++j) tmx[j] = fmaxf(s0[j], s1[j]);
#pragma unroll
        for (int off = 8; off; off >>= 1)
#pragma unroll
            for (int j = 0; j < 4; ++j) tmx[j] = fmaxf(tmx[j], __shfl_xor(tmx[j], off));

        f32x4 sc, p0, p1;
#pragma unroll
        for (int j = 0; j < 4; ++j) {
            const float mn = fmaxf(m[j], tmx[j]);
            sc[j] = __expf(m[j] - mn);
            p0[j] = __expf(s0[j] - mn);
            p1[j] = __expf(s1[j] - mn);
            m[j] = mn;
            ls[j] = ls[j] * sc[j] + p0[j] + p1[j];
        }
#pragma unroll
        for (int dt = 0; dt < 4; ++dt)
#pragma unroll
            for (int j = 0; j < 4; ++j) acc[dt][j] *= sc[j];

        // P -> LDS in C-layout; read back in A-frag layout. hi/lo bf16 split
        // keeps P at ~24-bit accuracy.
#pragma unroll
        for (int j = 0; j < 4; ++j) {
            const int r = 4 * g + j;
            const bf16 h0 = (bf16)p0[j];
            const bf16 h1 = (bf16)p1[j];
            Pl[w][r][lc]      = h0;
            Pl[w][r][16 + lc] = h1;
            Pl[w][r][48 + lc] = (bf16)(p0[j] - (float)h0);
            Pl[w][r][64 + lc] = (bf16)(p1[j] - (float)h1);
        }
        const bf16x8 pah = *(const bf16x8*)&Pl[w][lc][g * 8];
        const bf16x8 pal = *(const bf16x8*)&Pl[w][lc][48 + g * 8];

        // PV: B-frag of V^T from swizzled LDS tile
#pragma unroll
        for (int dt = 0; dt < 4; ++dt) {
            const int vr = dt * 16 + lc;
            const bf16x8 vf = *(const bf16x8*)(VT + vr * 64 + 16 * (g ^ ((vr >> 1) & 3)));
            acc[dt] = __builtin_amdgcn_mfma_f32_16x16x32_bf16(pah, vf, acc[dt], 0, 0, 0);
            acc[dt] = __builtin_amdgcn_mfma_f32_16x16x32_bf16(pal, vf, acc[dt], 0, 0, 0);
        }
    };

    stage(0);
    __syncthreads();                       // vmcnt drain: tile 0 visible
    for (int t = 0; t < NT; ++t) {
        if (t + 1 < NT) stage(t + 1);      // async into the other buffer
        if (t <= diag) compute(t, t == diag);
        __syncthreads();                   // publish tile t+1; reads of t done
    }

    // reduce lane-partial row sums across the 16 cols, normalize, store
    f32x4 inv;
#pragma unroll
    for (int j = 0; j < 4; ++j) {
        float s = ls[j];
#pragma unroll
        for (int off = 8; off; off >>= 1) s += __shfl_xor(s, off);
        inv[j] = 1.0f / s;
    }
    bf16* op = o + (size_t)(b * 1024 + qw) * 1024 + h * 64;
#pragma unroll
    for (int dt = 0; dt < 4; ++dt)
#pragma unroll
        for (int j = 0; j < 4; ++j)
            op[(size_t)(4 * g + j) * 1024 + dt * 16 + lc] = (bf16)(acc[dt][j] * inv[j]);
}

// ---------------------------------------------------------------------------
extern "C" void kernel_launch(void* const* d_in, const int* in_sizes, int n_in,
                              void* d_out, int out_size, void* d_ws, size_t ws_size,
                              hipStream_t stream)
{
    const int B = 2, S = 1024, D = 1024, L = 6, F = 4096, V = 32000, H = 16;
    const int M = B * S;

    const int*   tokens    = (const int*)  d_in[0];
    const float* token_emb = (const float*)d_in[1];
    const float* Wqkv      = (const float*)d_in[2];
    const float* Wout      = (const float*)d_in[3];
    const float* ln1_s     = (const float*)d_in[4];
    const float* ln1_b     = (const float*)d_in[5];
    const float* W1        = (const float*)d_in[6];
    const float* b1        = (const float*)d_in[7];
    const float* W2        = (const float*)d_in[8];
    const float* b2        = (const float*)d_in[9];
    const float* ln2_s     = (const float*)d_in[10];
    const float* ln2_b     = (const float*)d_in[11];
    const float* lnf_s     = (const float*)d_in[12];
    const float* lnf_b     = (const float*)d_in[13];
    const float* Whead     = (const float*)d_in[14];
    const float* bhead     = (const float*)d_in[15];
    float* out = (float*)d_out;

    char* w = (char*)d_ws;
    size_t off = 0;
    auto alloc = [&](size_t n) { char* p = w + off; off += (n + 255) & ~(size_t)255; return p; };
    bf16* WqkvT  = (bf16*)alloc((size_t)L * 3 * D * D * 2);
    bf16* WoutT  = (bf16*)alloc((size_t)L * D * D * 2);
    bf16* W1T    = (bf16*)alloc((size_t)L * F * D * 2);
    bf16* W2T    = (bf16*)alloc((size_t)L * D * F * 2);
    bf16* WheadT = (bf16*)alloc((size_t)V * D * 2);
    float* x     = (float*)alloc((size_t)M * D * 4);
    bf16* h      = (bf16*)alloc((size_t)M * D * 2);
    bf16* qkv    = (bf16*)alloc((size_t)M * 3 * D * 2);
    bf16* ob     = (bf16*)alloc((size_t)M * D * 2);
    bf16* mid    = (bf16*)alloc((size_t)M * F * 2);
    // vt aliases mid: vt is live only qkv-GEMM -> attn; mid only W1 -> W2.
    bf16* vt     = mid;   // [b][s/8][1024 hd][8] = 4 MB <= 16.8 MB

    // ---- merged weight transpose+cast (one launch) ----
    TSeg s0{Wqkv,  WqkvT,  D, 3 * D, 3 * D / 32, (3 * D / 32) * (D / 32), (3 * D / 32) * (D / 32) * L};
    TSeg s1{Wout,  WoutT,  D, D,     D / 32,     (D / 32) * (D / 32),     (D / 32) * (D / 32) * L};
    TSeg s2{W1,    W1T,    D, F,     F / 32,     (F / 32) * (D / 32),     (F / 32) * (D / 32) * L};
    TSeg s3{W2,    W2T,    F, D,     D / 32,     (D / 32) * (F / 32),     (D / 32) * (F / 32) * L};
    TSeg s4{Whead, WheadT, D, V,     V / 32,     (V / 32) * (D / 32),     (V / 32) * (D / 32)};
    const int totTiles = s0.nTiles + s1.nTiles + s2.nTiles + s3.nTiles + s4.nTiles;
    transpose_all_k<<<totTiles, dim3(32, 8), 0, stream>>>(s0, s1, s2, s3, s4);

    embed_k<<<M, 256, 0, stream>>>(tokens, token_emb, x);

    for (int lyr = 0; lyr < L; ++lyr) {
        layernorm_k<<<M, 256, 0, stream>>>(x, ln1_s + lyr * D, ln1_b + lyr * D, h);
        // qkv GEMM: Q,K cols -> qkv buffer; V cols -> vt (s-blocked) directly
        gemm_bt_k<5><<<dim3(M / 128, 3 * D / 128), 256, 0, stream>>>(
            h, WqkvT + (size_t)lyr * 3 * D * D, nullptr, qkv, vt, nullptr, M, 3 * D, D);
        attn_mfma_k<<<B * H * S / 64, 256, 0, stream>>>(qkv, vt, ob);
        gemm_bt_k<1, 4><<<dim3(M / 128, D / 128, 4), 256, 0, stream>>>(
            ob, WoutT + (size_t)lyr * D * D, x, nullptr, nullptr, nullptr, M, D, D);
        layernorm_k<<<M, 256, 0, stream>>>(x, ln2_s + lyr * D, ln2_b + lyr * D, h);
        gemm_bt_k<2><<<dim3(M / 128, F / 128), 256, 0, stream>>>(
            h, W1T + (size_t)lyr * F * D, nullptr, mid, nullptr, b1 + lyr * F, M, F, D);
        gemm_bt_k<3, 4><<<dim3(M / 128, D / 128, 4), 256, 0, stream>>>(
            mid, W2T + (size_t)lyr * D * F, x, nullptr, nullptr, b2 + lyr * D, M, D, F);
    }
    layernorm_k<<<M, 256, 0, stream>>>(x, lnf_s, lnf_b, h);
    gemm_bt_k<4><<<dim3(M / 128, V / 128), 256, 0, stream>>>(
        h, WheadT, out, nullptr, nullptr, bhead, M, V, D);
}

// Round 5
// 1584.851 us; speedup vs baseline: 1.0063x; 1.0063x over previous
//
#include <hip/hip_runtime.h>
#include <hip/hip_bf16.h>
#include <math.h>

typedef __bf16 bf16;
typedef __bf16 bf16x4 __attribute__((ext_vector_type(4)));
typedef __bf16 bf16x8 __attribute__((ext_vector_type(8)));
typedef float f32x4 __attribute__((ext_vector_type(4)));

#define GL_AS(p) ((const __attribute__((address_space(1))) void*)(p))
#define LDS_AS(p) ((__attribute__((address_space(3))) void*)(p))

// ---------------------------------------------------------------------------
// Bijective XCD-chunked remap (m204): hw round-robin -> contiguous chunk/XCD
// ---------------------------------------------------------------------------
__device__ inline void xcd_remap(int& bm, int& bn, int NBM, int NBN)
{
    const int nwg = NBM * NBN;
    const int flat = bm + NBM * bn;
    const int q = nwg >> 3, r = nwg & 7;
    const int x = flat & 7, i = flat >> 3;
    const int f2 = ((x < r) ? x * (q + 1) : r * (q + 1) + (x - r) * q) + i;
    bm = f2 % NBM;
    bn = f2 / NBM;
}

// ---------------------------------------------------------------------------
// Merged transpose + f32->bf16 cast for all 5 weight groups.
// ---------------------------------------------------------------------------
struct TSeg {
    const float* in; bf16* out; int R, C, nTilesC, tilesPerZ, nTiles;
};

__global__ __launch_bounds__(256) void transpose_all_k(
    TSeg s0, TSeg s1, TSeg s2, TSeg s3, TSeg s4)
{
    int t = blockIdx.x;
    TSeg s;
    if (t < s0.nTiles) s = s0;
    else { t -= s0.nTiles;
    if (t < s1.nTiles) s = s1;
    else { t -= s1.nTiles;
    if (t < s2.nTiles) s = s2;
    else { t -= s2.nTiles;
    if (t < s3.nTiles) s = s3;
    else { t -= s3.nTiles; s = s4; }}}}

    const int z   = t / s.tilesPerZ;
    const int rem = t - z * s.tilesPerZ;
    const int cx  = rem % s.nTilesC, ry = rem / s.nTilesC;

    __shared__ float tl[32][33];
    const int c0 = cx * 32, r0 = ry * 32;
    const size_t zoff = (size_t)z * s.R * s.C;
    const float* inb = s.in + zoff;
    bf16* outb = s.out + zoff;
    const int tx = threadIdx.x, ty = threadIdx.y;   // (32, 8)
#pragma unroll
    for (int i = 0; i < 32; i += 8)
        tl[ty + i][tx] = inb[(size_t)(r0 + ty + i) * s.C + c0 + tx];
    __syncthreads();
#pragma unroll
    for (int i = 0; i < 32; i += 8)
        outb[(size_t)(c0 + ty + i) * s.R + r0 + tx] = (bf16)tl[tx][ty + i];
}

// ---------------------------------------------------------------------------
// Embedding + sinusoidal positional encoding -> x f32 [B*S, 1024]
// ---------------------------------------------------------------------------
__global__ __launch_bounds__(256) void embed_k(
    const int* __restrict__ tok, const float* __restrict__ emb,
    float* __restrict__ x)
{
    const int D = 1024;
    const int row = blockIdx.x;
    const int s = row & 1023;          // S = 1024
    const int t = tok[row];
    const int d0 = threadIdx.x * 4;
    const float c = 9.210340371976184f / 512.0f;
    const float div0 = expf(-(float)(d0 >> 1) * c);
    const float div1 = expf(-(float)((d0 >> 1) + 1) * c);
    const float a0 = (float)s * div0, a1 = (float)s * div1;
    const f32x4 e = *(const f32x4*)(emb + (size_t)t * D + d0);
    f32x4 o;
    o[0] = e[0] + sinf(a0);
    o[1] = e[1] + cosf(a0);
    o[2] = e[2] + sinf(a1);
    o[3] = e[3] + cosf(a1);
    *(f32x4*)(x + (size_t)row * D + d0) = o;
}

// ---------------------------------------------------------------------------
// LayerNorm (D=1024): x f32 -> out bf16, vectorized 4 elems/thread
// ---------------------------------------------------------------------------
__global__ __launch_bounds__(256) void layernorm_k(
    const float* __restrict__ x, const float* __restrict__ sc,
    const float* __restrict__ bi, bf16* __restrict__ out)
{
    const int D = 1024;
    const int row = blockIdx.x;
    const int d0 = threadIdx.x * 4;
    const f32x4 v = *(const f32x4*)(x + (size_t)row * D + d0);
    float s = v[0] + v[1] + v[2] + v[3];
    float q = v[0] * v[0] + v[1] * v[1] + v[2] * v[2] + v[3] * v[3];
#pragma unroll
    for (int o = 32; o; o >>= 1) { s += __shfl_xor(s, o); q += __shfl_xor(q, o); }
    __shared__ float ls[4], lq[4];
    const int w = threadIdx.x >> 6;
    if ((threadIdx.x & 63) == 0) { ls[w] = s; lq[w] = q; }
    __syncthreads();
    const float S = ls[0] + ls[1] + ls[2] + ls[3];
    const float Q = lq[0] + lq[1] + lq[2] + lq[3];
    const float mu = S * (1.0f / D);
    const float var = Q * (1.0f / D) - mu * mu;
    const float rstd = rsqrtf(var + 1e-5f);
    const f32x4 sc4 = *(const f32x4*)(sc + d0);
    const f32x4 bi4 = *(const f32x4*)(bi + d0);
    bf16x4 o4;
#pragma unroll
    for (int i = 0; i < 4; ++i) o4[i] = (bf16)((v[i] - mu) * rstd * sc4[i] + bi4[i]);
    *(bf16x4*)(out + (size_t)row * D + d0) = o4;
}

// ---------------------------------------------------------------------------
// GEMM: C[M,N] = A[M,K](bf16) @ Bt[N,K](bf16)^T, f32 accum, various epilogues
// 128x128 tile, BK=64, 4 waves (2x2), mfma_f32_16x16x32_bf16, XCD-swizzled
// EPI: 0 store bf16 | 1 Cf += acc (atomic if SK>1) | 2 bias+gelu->bf16
//      3 Cf += acc+bias (atomic if SK>1) | 4 Cf = acc+bias
//      5 qkv write: cols<2048 -> Cb, cols>=2048 -> Cb2 = vt[b][s/8][hd][8]
// ---------------------------------------------------------------------------
template <int EPI, int SK = 1>
__global__ __launch_bounds__(256, 2) void gemm_bt_k(
    const bf16* __restrict__ A, const bf16* __restrict__ Bt,
    float* __restrict__ Cf, bf16* __restrict__ Cb, bf16* __restrict__ Cb2,
    const float* __restrict__ bias, int M, int N, int K)
{
    __shared__ __align__(16) bf16 Al[128 * 64];
    __shared__ __align__(16) bf16 Bl[128 * 64];
    const int tid = threadIdx.x;
    const int l = tid & 63;
    const int wbase = tid & 192;                 // wave_id * 64
    const int wr = (tid >> 7) & 1, wc = (tid >> 6) & 1;
    int bm = blockIdx.x, bn = blockIdx.y;
    xcd_remap(bm, bn, gridDim.x, gridDim.y);
    const int kz = blockIdx.z;
    const int Kc = K / SK;                       // this slice's K extent

    f32x4 acc[4][4];
#pragma unroll
    for (int i = 0; i < 4; ++i)
#pragma unroll
        for (int j = 0; j < 4; ++j) acc[i][j] = (f32x4){0.f, 0.f, 0.f, 0.f};

    const bf16* Abase = A + (size_t)bm * 128 * K + (size_t)kz * Kc;
    const bf16* Bbase = Bt + (size_t)bn * 128 * K + (size_t)kz * Kc;

    for (int k0 = 0; k0 < Kc; k0 += 64) {
#pragma unroll
        for (int i = 0; i < 4; ++i) {
            const int c = i * 256 + tid;
            const int row = c >> 3, slot = c & 7;
            const int col = ((slot ^ (row & 7)) << 3);
            __builtin_amdgcn_global_load_lds(
                GL_AS(Abase + (size_t)row * K + k0 + col),
                LDS_AS(Al + (i * 256 + wbase) * 8), 16, 0, 0);
        }
#pragma unroll
        for (int i = 0; i < 4; ++i) {
            const int c = i * 256 + tid;
            const int row = c >> 3, slot = c & 7;
            const int col = ((slot ^ (row & 7)) << 3);
            __builtin_amdgcn_global_load_lds(
                GL_AS(Bbase + (size_t)row * K + k0 + col),
                LDS_AS(Bl + (i * 256 + wbase) * 8), 16, 0, 0);
        }
        __syncthreads();   // drains vmcnt: tiles visible

#pragma unroll
        for (int ks = 0; ks < 2; ++ks) {
            bf16x8 af[4], bfr[4];
            const int kb = ks * 64 + ((l >> 4) << 4);
#pragma unroll
            for (int mi = 0; mi < 4; ++mi) {
                const int r = wr * 64 + mi * 16 + (l & 15);
                af[mi] = *(const bf16x8*)((const char*)Al + r * 128 + (kb ^ ((r & 7) << 4)));
            }
#pragma unroll
            for (int ni = 0; ni < 4; ++ni) {
                const int r = wc * 64 + ni * 16 + (l & 15);
                bfr[ni] = *(const bf16x8*)((const char*)Bl + r * 128 + (kb ^ ((r & 7) << 4)));
            }
#pragma unroll
            for (int mi = 0; mi < 4; ++mi)
#pragma unroll
                for (int ni = 0; ni < 4; ++ni)
                    acc[mi][ni] = __builtin_amdgcn_mfma_f32_16x16x32_bf16(
                        af[mi], bfr[ni], acc[mi][ni], 0, 0, 0);
        }
        __syncthreads();
    }

    // ---- epilogue: C/D layout col=lane&15, row=(lane>>4)*4+j  [m89/m91]
    const int colb = bn * 128 + wc * 64;
    const int rowb = bm * 128 + wr * 64 + ((l >> 4) << 2);
#pragma unroll
    for (int mi = 0; mi < 4; ++mi) {
#pragma unroll
        for (int ni = 0; ni < 4; ++ni) {
            const int col = colb + ni * 16 + (l & 15);
            if constexpr (EPI == 5) {
                const int row0 = rowb + mi * 16;
                if (col < 2048) {
#pragma unroll
                    for (int j = 0; j < 4; ++j)
                        Cb[(size_t)(row0 + j) * N + col] = (bf16)acc[mi][ni][j];
                } else {
                    bf16x4 v4;
#pragma unroll
                    for (int j = 0; j < 4; ++j) v4[j] = (bf16)acc[mi][ni][j];
                    *(bf16x4*)&Cb2[((size_t)(row0 >> 3) * 1024 + (col - 2048)) * 8 + (row0 & 7)] = v4;
                }
            } else {
#pragma unroll
                for (int j = 0; j < 4; ++j) {
                    const int row = rowb + mi * 16 + j;
                    const float v = acc[mi][ni][j];
                    if constexpr (EPI == 0) {
                        Cb[(size_t)row * N + col] = (bf16)v;
                    } else if constexpr (EPI == 1) {
                        if constexpr (SK > 1) atomicAdd(&Cf[(size_t)row * N + col], v);
                        else                  Cf[(size_t)row * N + col] += v;
                    } else if constexpr (EPI == 2) {
                        const float u = v + bias[col];
                        const float g = 0.5f * u * (1.0f + erff(u * 0.70710678118654752f));
                        Cb[(size_t)row * N + col] = (bf16)g;
                    } else if constexpr (EPI == 3) {
                        const float add = (SK == 1 || kz == 0) ? v + bias[col] : v;
                        if constexpr (SK > 1) atomicAdd(&Cf[(size_t)row * N + col], add);
                        else                  Cf[(size_t)row * N + col] += add;
                    } else if constexpr (EPI == 4) {
                        Cf[(size_t)row * N + col] = v + bias[col];
                    }
                }
            }
        }
    }
}

// ---------------------------------------------------------------------------
// 256x256 8-phase GEMM (m201-style, plain HIP): Cf = A@Bt^T + bias.
// 8 waves (2M x 4N), BK=64, per-wave 128x64, acc[8][4]. LDS 128 KB:
// 2 buffers x ([256x64] A + [256x64] B), XOR-swizzled 16B slots.
// Phases per K-tile: ph1 (mh0,nh0: 12 ds_reads), ph2 (nh1: 4), ph3 (mh1: 8),
// ph4 (0; b0 kept in regs). 16 MFMA each, setprio-wrapped, raw s_barrier.
// Stage slots (2 global_load_lds each): ph1/ph2 -> A halves of tile t+1
// (other buffer); ph3/ph4 -> B halves of tile t+2 (current buffer; B's LDS
// reads finish at ph2). vmcnt(4) once per K-tile at ph4: leaves exactly the
// two just-issued B halves (t+2) in flight, guarantees all of t+1 landed.
// ---------------------------------------------------------------------------
__global__ __launch_bounds__(512, 2) void gemm256_bias_k(
    const bf16* __restrict__ A, const bf16* __restrict__ Bt,
    float* __restrict__ Cf, const float* __restrict__ bias,
    int M, int N, int K)
{
    __shared__ __align__(16) bf16 Al[2][256 * 64];
    __shared__ __align__(16) bf16 Bl[2][256 * 64];
    const int tid = threadIdx.x;
    const int l = tid & 63;
    const int wid = tid >> 6;            // 0..7
    const int wm = wid >> 2, wn = wid & 3;
    const int g = l >> 4, lc = l & 15;
    int bm = blockIdx.x, bn = blockIdx.y;
    xcd_remap(bm, bn, gridDim.x, gridDim.y);

    const bf16* Ab = A + (size_t)bm * 256 * K;
    const bf16* Bb = Bt + (size_t)bn * 256 * K;
    const int NT = K >> 6;

    f32x4 acc[8][4];
#pragma unroll
    for (int i = 0; i < 8; ++i)
#pragma unroll
        for (int j = 0; j < 4; ++j) acc[i][j] = (f32x4){0.f, 0.f, 0.f, 0.f};

    // stage one 128-row half of a [256x64] tile: 2 chunks of 16B per thread
    auto stageA = [&](int t, int mh) {
        bf16* dst = Al[t & 1] + mh * 8192;
#pragma unroll
        for (int ld = 0; ld < 2; ++ld) {
            const int c = ld * 512 + tid;           // 0..1023
            const int r = c >> 3, slot = c & 7;
            const int col = ((slot ^ (r & 7)) << 3);
            __builtin_amdgcn_global_load_lds(
                GL_AS(Ab + (size_t)(mh * 128 + r) * K + t * 64 + col),
                LDS_AS(dst + (ld * 512 + (tid & 448)) * 8), 16, 0, 0);
        }
    };
    auto stageB = [&](int t, int nh) {
        bf16* dst = Bl[t & 1] + nh * 8192;
#pragma unroll
        for (int ld = 0; ld < 2; ++ld) {
            const int c = ld * 512 + tid;
            const int r = c >> 3, slot = c & 7;
            const int col = ((slot ^ (r & 7)) << 3);
            __builtin_amdgcn_global_load_lds(
                GL_AS(Bb + (size_t)(nh * 128 + r) * K + t * 64 + col),
                LDS_AS(dst + (ld * 512 + (tid & 448)) * 8), 16, 0, 0);
        }
    };
    auto ldA = [&](bf16x8 (&a)[4][2], int mh, int p) {
#pragma unroll
        for (int i = 0; i < 4; ++i) {
            const int r = wm * 128 + mh * 64 + i * 16 + lc;
            const char* base = (const char*)Al[p] + r * 128;
#pragma unroll
            for (int ks = 0; ks < 2; ++ks)
                a[i][ks] = *(const bf16x8*)(base + ((ks * 64 + g * 16) ^ ((r & 7) << 4)));
        }
    };
    auto ldB = [&](bf16x8 (&b)[2][2], int nh, int p) {
#pragma unroll
        for (int i = 0; i < 2; ++i) {
            const int r = wn * 64 + nh * 32 + i * 16 + lc;
            const char* base = (const char*)Bl[p] + r * 128;
#pragma unroll
            for (int ks = 0; ks < 2; ++ks)
                b[i][ks] = *(const bf16x8*)(base + ((ks * 64 + g * 16) ^ ((r & 7) << 4)));
        }
    };
    auto mm = [&](bf16x8 (&a)[4][2], bf16x8 (&b)[2][2], int mh, int nh) {
        __builtin_amdgcn_s_setprio(1);
#pragma unroll
        for (int i = 0; i < 4; ++i)
#pragma unroll
            for (int jn = 0; jn < 2; ++jn) {
                f32x4 ac = acc[mh * 4 + i][nh * 2 + jn];
                ac = __builtin_amdgcn_mfma_f32_16x16x32_bf16(a[i][0], b[jn][0], ac, 0, 0, 0);
                ac = __builtin_amdgcn_mfma_f32_16x16x32_bf16(a[i][1], b[jn][1], ac, 0, 0, 0);
                acc[mh * 4 + i][nh * 2 + jn] = ac;
            }
        __builtin_amdgcn_s_setprio(0);
    };

    // prologue: tile0 fully + tile1's B halves; wait until tile0 landed (8 loads)
    stageB(0, 0); stageB(0, 1); stageA(0, 0); stageA(0, 1);
    if (NT > 1) { stageB(1, 0); stageB(1, 1); }
    asm volatile("s_waitcnt vmcnt(4)" ::: "memory");
    __builtin_amdgcn_s_barrier();

    for (int t = 0; t < NT; ++t) {
        const int p = t & 1;
        bf16x8 a[4][2], b0[2][2], b1[2][2];
        // ---- ph1: (mh0, nh0)
        ldA(a, 0, p); ldB(b0, 0, p);
        if (t + 1 < NT) stageA(t + 1, 0);
        __builtin_amdgcn_s_barrier();
        mm(a, b0, 0, 0);
        __builtin_amdgcn_s_barrier();
        // ---- ph2: (mh0, nh1)
        ldB(b1, 1, p);
        if (t + 1 < NT) stageA(t + 1, 1);
        __builtin_amdgcn_s_barrier();
        mm(a, b1, 0, 1);
        __builtin_amdgcn_s_barrier();
        // ---- ph3: (mh1, nh1)
        ldA(a, 1, p);
        if (t + 2 < NT) stageB(t + 2, 0);
        __builtin_amdgcn_s_barrier();
        mm(a, b1, 1, 1);
        __builtin_amdgcn_s_barrier();
        // ---- ph4: (mh1, nh0); counted vmcnt (never 0): the two B halves of
        // t+2 may stay in flight; everything for t+1 is guaranteed landed.
        if (t + 2 < NT) stageB(t + 2, 1);
        asm volatile("s_waitcnt vmcnt(4)" ::: "memory");
        __builtin_amdgcn_s_barrier();
        mm(a, b0, 1, 0);
        __builtin_amdgcn_s_barrier();
    }

    // ---- epilogue
    const int colb = bn * 256 + wn * 64;
    const int rowb = bm * 256 + wm * 128 + g * 4;
#pragma unroll
    for (int mi = 0; mi < 8; ++mi) {
#pragma unroll
        for (int ni = 0; ni < 4; ++ni) {
            const int col = colb + ni * 16 + lc;
#pragma unroll
            for (int j = 0; j < 4; ++j) {
                const int row = rowb + mi * 16 + j;
                Cf[(size_t)row * N + col] = acc[mi][ni][j] + bias[col];
            }
        }
    }
}

// ---------------------------------------------------------------------------
// MFMA flash attention v2. 4 waves per block, 64 q-rows per block (16/wave).
// ---------------------------------------------------------------------------
__global__ __launch_bounds__(256) void attn_mfma_k(
    const bf16* __restrict__ qkv, const bf16* __restrict__ vt,
    bf16* __restrict__ o)
{
    __shared__ __align__(16) bf16 Kl[2][32 * 64];
    __shared__ __align__(16) bf16 Vl[2][64 * 32];
    __shared__ __align__(16) bf16 Pl[4][16][88];   // per-wave P round-trip

    const int tid = threadIdx.x;
    const int w = tid >> 6, l = tid & 63;
    const int g = l >> 4, lc = l & 15;
    const int qt = blockIdx.x & 15;      // S/64 = 16 q-blocks
    const int bh = blockIdx.x >> 4;
    const int h = bh & 15, b = bh >> 4;
    const int q0 = qt * 64;
    const int qw = q0 + w * 16;          // this wave's q-subtile
    const int diag = qw >> 5;            // wave's diagonal (masked) tile
    const int NT = (q0 >> 5) + 2;        // tiles staged by this block

    const bf16* qbase = qkv + (size_t)b * 1024 * 3072 + h * 64;
    const bf16* kbase = qbase + 1024;
    const bf16* vbase = vt + (size_t)b * 128 * 8192 + h * 64 * 8;

    bf16x8 af0, af1;
    {
        const bf16* qp = qbase + (size_t)(qw + lc) * 3072 + g * 8;
        af0 = *(const bf16x8*)qp;
        af1 = *(const bf16x8*)(qp + 32);
    }

    f32x4 acc[4];
#pragma unroll
    for (int dt = 0; dt < 4; ++dt) acc[dt] = (f32x4){0.f, 0.f, 0.f, 0.f};
    f32x4 m  = (f32x4){-1e30f, -1e30f, -1e30f, -1e30f};
    f32x4 ls = (f32x4){0.f, 0.f, 0.f, 0.f};

    auto stage = [&](int t) {
        const int k0 = t * 32;
        const int buf = t & 1;
        {
            const int row = tid >> 3;
            const int d = (((tid & 7) ^ (row & 7)) << 3);
            __builtin_amdgcn_global_load_lds(
                GL_AS(kbase + (size_t)(k0 + row) * 3072 + d),
                LDS_AS(Kl[buf] + (tid & 192) * 8), 16, 0, 0);
        }
        {
            const int row = tid >> 2;
            const int so = (tid & 3) ^ ((tid >> 3) & 3);
            __builtin_amdgcn_global_load_lds(
                GL_AS(vbase + (size_t)((k0 >> 3) + so) * 8192 + row * 8),
                LDS_AS(Vl[buf] + (tid & 192) * 8), 16, 0, 0);
        }
    };

    auto compute = [&](int t, bool MASKED) {
        const char* KT = (const char*)Kl[t & 1];
        const char* VT = (const char*)Vl[t & 1];
        const int k0 = t * 32;

        const int r0 = lc, r1 = 16 + lc;
        const bf16x8 kf00 = *(const bf16x8*)(KT + r0 * 128 + 16 * (g       ^ (r0 & 7)));
        const bf16x8 kf01 = *(const bf16x8*)(KT + r0 * 128 + 16 * ((4 + g) ^ (r0 & 7)));
        const bf16x8 kf10 = *(const bf16x8*)(KT + r1 * 128 + 16 * (g       ^ (r1 & 7)));
        const bf16x8 kf11 = *(const bf16x8*)(KT + r1 * 128 + 16 * ((4 + g) ^ (r1 & 7)));

        f32x4 s0 = (f32x4){0.f, 0.f, 0.f, 0.f};
        f32x4 s1 = (f32x4){0.f, 0.f, 0.f, 0.f};
        s0 = __builtin_amdgcn_mfma_f32_16x16x32_bf16(af0, kf00, s0, 0, 0, 0);
        s0 = __builtin_amdgcn_mfma_f32_16x16x32_bf16(af1, kf01, s0, 0, 0, 0);
        s1 = __builtin_amdgcn_mfma_f32_16x16x32_bf16(af0, kf10, s1, 0, 0, 0);
        s1 = __builtin_amdgcn_mfma_f32_16x16x32_bf16(af1, kf11, s1, 0, 0, 0);

#pragma unroll
        for (int j = 0; j < 4; ++j) {
            if (MASKED) {
                const int row = qw + 4 * g + j;
                s0[j] = (k0 + lc <= row)      ? s0[j] * 0.125f : -1e30f;
                s1[j] = (k0 + 16 + lc <= row) ? s1[j] * 0.125f : -1e30f;
            } else {
                s0[j] *= 0.125f;
                s1[j] *= 0.125f;
            }
        }

        f32x4 tmx;
#pragma unroll
        for (int j = 0; j < 4; ++j) tmx[j] = fmaxf(s0[j], s1[j]);
#pragma unroll
        for (int off = 8; off; off >>= 1)
#pragma unroll
            for (int j = 0; j < 4; ++j) tmx[j] = fmaxf(tmx[j], __shfl_xor(tmx[j], off));

        f32x4 sc, p0, p1;
#pragma unroll
        for (int j = 0; j < 4; ++j) {
            const float mn = fmaxf(m[j], tmx[j]);
            sc[j] = __expf(m[j] - mn);
            p0[j] = __expf(s0[j] - mn);
            p1[j] = __expf(s1[j] - mn);
            m[j] = mn;
            ls[j] = ls[j] * sc[j] + p0[j] + p1[j];
        }
#pragma unroll
        for (int dt = 0; dt < 4; ++dt)
#pragma unroll
            for (int j = 0; j < 4; ++j) acc[dt][j] *= sc[j];

#pragma unroll
        for (int j = 0; j < 4; ++j) {
            const int r = 4 * g + j;
            const bf16 h0 = (bf16)p0[j];
            const bf16 h1 = (bf16)p1[j];
            Pl[w][r][lc]      = h0;
            Pl[w][r][16 + lc] = h1;
            Pl[w][r][48 + lc] = (bf16)(p0[j] - (float)h0);
            Pl[w][r][64 + lc] = (bf16)(p1[j] - (float)h1);
        }
        const bf16x8 pah = *(const bf16x8*)&Pl[w][lc][g * 8];
        const bf16x8 pal = *(const bf16x8*)&Pl[w][lc][48 + g * 8];

#pragma unroll
        for (int dt = 0; dt < 4; ++dt) {
            const int vr = dt * 16 + lc;
            const bf16x8 vf = *(const bf16x8*)(VT + vr * 64 + 16 * (g ^ ((vr >> 1) & 3)));
            acc[dt] = __builtin_amdgcn_mfma_f32_16x16x32_bf16(pah, vf, acc[dt], 0, 0, 0);
            acc[dt] = __builtin_amdgcn_mfma_f32_16x16x32_bf16(pal, vf, acc[dt], 0, 0, 0);
        }
    };

    stage(0);
    __syncthreads();
    for (int t = 0; t < NT; ++t) {
        if (t + 1 < NT) stage(t + 1);
        if (t <= diag) compute(t, t == diag);
        __syncthreads();
    }

    f32x4 inv;
#pragma unroll
    for (int j = 0; j < 4; ++j) {
        float s = ls[j];
#pragma unroll
        for (int off = 8; off; off >>= 1) s += __shfl_xor(s, off);
        inv[j] = 1.0f / s;
    }
    bf16* op = o + (size_t)(b * 1024 + qw) * 1024 + h * 64;
#pragma unroll
    for (int dt = 0; dt < 4; ++dt)
#pragma unroll
        for (int j = 0; j < 4; ++j)
            op[(size_t)(4 * g + j) * 1024 + dt * 16 + lc] = (bf16)(acc[dt][j] * inv[j]);
}

// ---------------------------------------------------------------------------
extern "C" void kernel_launch(void* const* d_in, const int* in_sizes, int n_in,
                              void* d_out, int out_size, void* d_ws, size_t ws_size,
                              hipStream_t stream)
{
    const int B = 2, S = 1024, D = 1024, L = 6, F = 4096, V = 32000, H = 16;
    const int M = B * S;

    const int*   tokens    = (const int*)  d_in[0];
    const float* token_emb = (const float*)d_in[1];
    const float* Wqkv      = (const float*)d_in[2];
    const float* Wout      = (const float*)d_in[3];
    const float* ln1_s     = (const float*)d_in[4];
    const float* ln1_b     = (const float*)d_in[5];
    const float* W1        = (const float*)d_in[6];
    const float* b1        = (const float*)d_in[7];
    const float* W2        = (const float*)d_in[8];
    const float* b2        = (const float*)d_in[9];
    const float* ln2_s     = (const float*)d_in[10];
    const float* ln2_b     = (const float*)d_in[11];
    const float* lnf_s     = (const float*)d_in[12];
    const float* lnf_b     = (const float*)d_in[13];
    const float* Whead     = (const float*)d_in[14];
    const float* bhead     = (const float*)d_in[15];
    float* out = (float*)d_out;

    char* w = (char*)d_ws;
    size_t off = 0;
    auto alloc = [&](size_t n) { char* p = w + off; off += (n + 255) & ~(size_t)255; return p; };
    bf16* WqkvT  = (bf16*)alloc((size_t)L * 3 * D * D * 2);
    bf16* WoutT  = (bf16*)alloc((size_t)L * D * D * 2);
    bf16* W1T    = (bf16*)alloc((size_t)L * F * D * 2);
    bf16* W2T    = (bf16*)alloc((size_t)L * D * F * 2);
    bf16* WheadT = (bf16*)alloc((size_t)V * D * 2);
    float* x     = (float*)alloc((size_t)M * D * 4);
    bf16* h      = (bf16*)alloc((size_t)M * D * 2);
    bf16* qkv    = (bf16*)alloc((size_t)M * 3 * D * 2);
    bf16* ob     = (bf16*)alloc((size_t)M * D * 2);
    bf16* mid    = (bf16*)alloc((size_t)M * F * 2);
    bf16* vt     = mid;   // [b][s/8][1024 hd][8] = 4 MB, aliases mid

    TSeg s0{Wqkv,  WqkvT,  D, 3 * D, 3 * D / 32, (3 * D / 32) * (D / 32), (3 * D / 32) * (D / 32) * L};
    TSeg s1{Wout,  WoutT,  D, D,     D / 32,     (D / 32) * (D / 32),     (D / 32) * (D / 32) * L};
    TSeg s2{W1,    W1T,    D, F,     F / 32,     (F / 32) * (D / 32),     (F / 32) * (D / 32) * L};
    TSeg s3{W2,    W2T,    F, D,     D / 32,     (D / 32) * (F / 32),     (D / 32) * (F / 32) * L};
    TSeg s4{Whead, WheadT, D, V,     V / 32,     (V / 32) * (D / 32),     (V / 32) * (D / 32)};
    const int totTiles = s0.nTiles + s1.nTiles + s2.nTiles + s3.nTiles + s4.nTiles;
    transpose_all_k<<<totTiles, dim3(32, 8), 0, stream>>>(s0, s1, s2, s3, s4);

    embed_k<<<M, 256, 0, stream>>>(tokens, token_emb, x);

    for (int lyr = 0; lyr < L; ++lyr) {
        layernorm_k<<<M, 256, 0, stream>>>(x, ln1_s + lyr * D, ln1_b + lyr * D, h);
        gemm_bt_k<5><<<dim3(M / 128, 3 * D / 128), 256, 0, stream>>>(
            h, WqkvT + (size_t)lyr * 3 * D * D, nullptr, qkv, vt, nullptr, M, 3 * D, D);
        attn_mfma_k<<<B * H * S / 64, 256, 0, stream>>>(qkv, vt, ob);
        gemm_bt_k<1, 4><<<dim3(M / 128, D / 128, 4), 256, 0, stream>>>(
            ob, WoutT + (size_t)lyr * D * D, x, nullptr, nullptr, nullptr, M, D, D);
        layernorm_k<<<M, 256, 0, stream>>>(x, ln2_s + lyr * D, ln2_b + lyr * D, h);
        gemm_bt_k<2><<<dim3(M / 128, F / 128), 256, 0, stream>>>(
            h, W1T + (size_t)lyr * F * D, nullptr, mid, nullptr, b1 + lyr * F, M, F, D);
        gemm_bt_k<3, 4><<<dim3(M / 128, D / 128, 4), 256, 0, stream>>>(
            mid, W2T + (size_t)lyr * D * F, x, nullptr, nullptr, b2 + lyr * D, M, D, F);
    }
    layernorm_k<<<M, 256, 0, stream>>>(x, lnf_s, lnf_b, h);
    // head: 256x256 8-phase kernel, grid 8 x 125 = 1000 blocks
    gemm256_bias_k<<<dim3(M / 256, V / 256), 512, 0, stream>>>(
        h, WheadT, out, bhead, M, V, D);
}

// Round 6
// 1511.094 us; speedup vs baseline: 1.0555x; 1.0488x over previous
//
#include <hip/hip_runtime.h>
#include <hip/hip_bf16.h>
#include <math.h>

typedef __bf16 bf16;
typedef __bf16 bf16x4 __attribute__((ext_vector_type(4)));
typedef __bf16 bf16x8 __attribute__((ext_vector_type(8)));
typedef float f32x4 __attribute__((ext_vector_type(4)));

#define GL_AS(p) ((const __attribute__((address_space(1))) void*)(p))
#define LDS_AS(p) ((__attribute__((address_space(3))) void*)(p))

// ---------------------------------------------------------------------------
// Bijective XCD-chunked remap (m204): hw round-robin -> contiguous chunk/XCD
// ---------------------------------------------------------------------------
__device__ inline void xcd_remap(int& bm, int& bn, int NBM, int NBN)
{
    const int nwg = NBM * NBN;
    const int flat = bm + NBM * bn;
    const int q = nwg >> 3, r = nwg & 7;
    const int x = flat & 7, i = flat >> 3;
    const int f2 = ((x < r) ? x * (q + 1) : r * (q + 1) + (x - r) * q) + i;
    bm = f2 % NBM;
    bn = f2 / NBM;
}

// ---------------------------------------------------------------------------
// Merged transpose + f32->bf16 cast for all 5 weight groups.
// ---------------------------------------------------------------------------
struct TSeg {
    const float* in; bf16* out; int R, C, nTilesC, tilesPerZ, nTiles;
};

__global__ __launch_bounds__(256) void transpose_all_k(
    TSeg s0, TSeg s1, TSeg s2, TSeg s3, TSeg s4)
{
    int t = blockIdx.x;
    TSeg s;
    if (t < s0.nTiles) s = s0;
    else { t -= s0.nTiles;
    if (t < s1.nTiles) s = s1;
    else { t -= s1.nTiles;
    if (t < s2.nTiles) s = s2;
    else { t -= s2.nTiles;
    if (t < s3.nTiles) s = s3;
    else { t -= s3.nTiles; s = s4; }}}}

    const int z   = t / s.tilesPerZ;
    const int rem = t - z * s.tilesPerZ;
    const int cx  = rem % s.nTilesC, ry = rem / s.nTilesC;

    __shared__ float tl[32][33];
    const int c0 = cx * 32, r0 = ry * 32;
    const size_t zoff = (size_t)z * s.R * s.C;
    const float* inb = s.in + zoff;
    bf16* outb = s.out + zoff;
    const int tx = threadIdx.x, ty = threadIdx.y;   // (32, 8)
#pragma unroll
    for (int i = 0; i < 32; i += 8)
        tl[ty + i][tx] = inb[(size_t)(r0 + ty + i) * s.C + c0 + tx];
    __syncthreads();
#pragma unroll
    for (int i = 0; i < 32; i += 8)
        outb[(size_t)(c0 + ty + i) * s.R + r0 + tx] = (bf16)tl[tx][ty + i];
}

// ---------------------------------------------------------------------------
// Embedding + sinusoidal positional encoding -> x f32 [B*S, 1024]
// ---------------------------------------------------------------------------
__global__ __launch_bounds__(256) void embed_k(
    const int* __restrict__ tok, const float* __restrict__ emb,
    float* __restrict__ x)
{
    const int D = 1024;
    const int row = blockIdx.x;
    const int s = row & 1023;          // S = 1024
    const int t = tok[row];
    const int d0 = threadIdx.x * 4;
    const float c = 9.210340371976184f / 512.0f;
    const float div0 = expf(-(float)(d0 >> 1) * c);
    const float div1 = expf(-(float)((d0 >> 1) + 1) * c);
    const float a0 = (float)s * div0, a1 = (float)s * div1;
    const f32x4 e = *(const f32x4*)(emb + (size_t)t * D + d0);
    f32x4 o;
    o[0] = e[0] + sinf(a0);
    o[1] = e[1] + cosf(a0);
    o[2] = e[2] + sinf(a1);
    o[3] = e[3] + cosf(a1);
    *(f32x4*)(x + (size_t)row * D + d0) = o;
}

// ---------------------------------------------------------------------------
// LayerNorm (D=1024): x f32 -> out bf16, vectorized 4 elems/thread
// ---------------------------------------------------------------------------
__global__ __launch_bounds__(256) void layernorm_k(
    const float* __restrict__ x, const float* __restrict__ sc,
    const float* __restrict__ bi, bf16* __restrict__ out)
{
    const int D = 1024;
    const int row = blockIdx.x;
    const int d0 = threadIdx.x * 4;
    const f32x4 v = *(const f32x4*)(x + (size_t)row * D + d0);
    float s = v[0] + v[1] + v[2] + v[3];
    float q = v[0] * v[0] + v[1] * v[1] + v[2] * v[2] + v[3] * v[3];
#pragma unroll
    for (int o = 32; o; o >>= 1) { s += __shfl_xor(s, o); q += __shfl_xor(q, o); }
    __shared__ float ls[4], lq[4];
    const int w = threadIdx.x >> 6;
    if ((threadIdx.x & 63) == 0) { ls[w] = s; lq[w] = q; }
    __syncthreads();
    const float S = ls[0] + ls[1] + ls[2] + ls[3];
    const float Q = lq[0] + lq[1] + lq[2] + lq[3];
    const float mu = S * (1.0f / D);
    const float var = Q * (1.0f / D) - mu * mu;
    const float rstd = rsqrtf(var + 1e-5f);
    const f32x4 sc4 = *(const f32x4*)(sc + d0);
    const f32x4 bi4 = *(const f32x4*)(bi + d0);
    bf16x4 o4;
#pragma unroll
    for (int i = 0; i < 4; ++i) o4[i] = (bf16)((v[i] - mu) * rstd * sc4[i] + bi4[i]);
    *(bf16x4*)(out + (size_t)row * D + d0) = o4;
}

// ---------------------------------------------------------------------------
// GEMM: C[M,N] = A[M,K](bf16) @ Bt[N,K](bf16)^T, f32 accum, various epilogues
// 128x128 tile, BK=64, 4 waves (2x2), mfma_f32_16x16x32_bf16, XCD-swizzled
// EPI: 0 store bf16 | 1 Cf += acc (atomic if SK>1) | 2 bias+gelu->bf16
//      3 Cf += acc+bias (atomic if SK>1) | 4 Cf = acc+bias
//      5 qkv write: cols<2048 -> Cb, cols>=2048 -> Cb2 = vt[b][s/8][hd][8]
// ---------------------------------------------------------------------------
template <int EPI, int SK = 1>
__global__ __launch_bounds__(256, 2) void gemm_bt_k(
    const bf16* __restrict__ A, const bf16* __restrict__ Bt,
    float* __restrict__ Cf, bf16* __restrict__ Cb, bf16* __restrict__ Cb2,
    const float* __restrict__ bias, int M, int N, int K)
{
    __shared__ __align__(16) bf16 Al[128 * 64];
    __shared__ __align__(16) bf16 Bl[128 * 64];
    const int tid = threadIdx.x;
    const int l = tid & 63;
    const int wbase = tid & 192;                 // wave_id * 64
    const int wr = (tid >> 7) & 1, wc = (tid >> 6) & 1;
    int bm = blockIdx.x, bn = blockIdx.y;
    xcd_remap(bm, bn, gridDim.x, gridDim.y);
    const int kz = blockIdx.z;
    const int Kc = K / SK;                       // this slice's K extent

    f32x4 acc[4][4];
#pragma unroll
    for (int i = 0; i < 4; ++i)
#pragma unroll
        for (int j = 0; j < 4; ++j) acc[i][j] = (f32x4){0.f, 0.f, 0.f, 0.f};

    const bf16* Abase = A + (size_t)bm * 128 * K + (size_t)kz * Kc;
    const bf16* Bbase = Bt + (size_t)bn * 128 * K + (size_t)kz * Kc;

    for (int k0 = 0; k0 < Kc; k0 += 64) {
#pragma unroll
        for (int i = 0; i < 4; ++i) {
            const int c = i * 256 + tid;
            const int row = c >> 3, slot = c & 7;
            const int col = ((slot ^ (row & 7)) << 3);
            __builtin_amdgcn_global_load_lds(
                GL_AS(Abase + (size_t)row * K + k0 + col),
                LDS_AS(Al + (i * 256 + wbase) * 8), 16, 0, 0);
        }
#pragma unroll
        for (int i = 0; i < 4; ++i) {
            const int c = i * 256 + tid;
            const int row = c >> 3, slot = c & 7;
            const int col = ((slot ^ (row & 7)) << 3);
            __builtin_amdgcn_global_load_lds(
                GL_AS(Bbase + (size_t)row * K + k0 + col),
                LDS_AS(Bl + (i * 256 + wbase) * 8), 16, 0, 0);
        }
        __syncthreads();   // drains vmcnt: tiles visible

#pragma unroll
        for (int ks = 0; ks < 2; ++ks) {
            bf16x8 af[4], bfr[4];
            const int kb = ks * 64 + ((l >> 4) << 4);
#pragma unroll
            for (int mi = 0; mi < 4; ++mi) {
                const int r = wr * 64 + mi * 16 + (l & 15);
                af[mi] = *(const bf16x8*)((const char*)Al + r * 128 + (kb ^ ((r & 7) << 4)));
            }
#pragma unroll
            for (int ni = 0; ni < 4; ++ni) {
                const int r = wc * 64 + ni * 16 + (l & 15);
                bfr[ni] = *(const bf16x8*)((const char*)Bl + r * 128 + (kb ^ ((r & 7) << 4)));
            }
#pragma unroll
            for (int mi = 0; mi < 4; ++mi)
#pragma unroll
                for (int ni = 0; ni < 4; ++ni)
                    acc[mi][ni] = __builtin_amdgcn_mfma_f32_16x16x32_bf16(
                        af[mi], bfr[ni], acc[mi][ni], 0, 0, 0);
        }
        __syncthreads();
    }

    // ---- epilogue: C/D layout col=lane&15, row=(lane>>4)*4+j  [m89/m91]
    const int colb = bn * 128 + wc * 64;
    const int rowb = bm * 128 + wr * 64 + ((l >> 4) << 2);
#pragma unroll
    for (int mi = 0; mi < 4; ++mi) {
#pragma unroll
        for (int ni = 0; ni < 4; ++ni) {
            const int col = colb + ni * 16 + (l & 15);
            if constexpr (EPI == 5) {
                const int row0 = rowb + mi * 16;
                if (col < 2048) {
#pragma unroll
                    for (int j = 0; j < 4; ++j)
                        Cb[(size_t)(row0 + j) * N + col] = (bf16)acc[mi][ni][j];
                } else {
                    bf16x4 v4;
#pragma unroll
                    for (int j = 0; j < 4; ++j) v4[j] = (bf16)acc[mi][ni][j];
                    *(bf16x4*)&Cb2[((size_t)(row0 >> 3) * 1024 + (col - 2048)) * 8 + (row0 & 7)] = v4;
                }
            } else {
#pragma unroll
                for (int j = 0; j < 4; ++j) {
                    const int row = rowb + mi * 16 + j;
                    const float v = acc[mi][ni][j];
                    if constexpr (EPI == 0) {
                        Cb[(size_t)row * N + col] = (bf16)v;
                    } else if constexpr (EPI == 1) {
                        if constexpr (SK > 1) atomicAdd(&Cf[(size_t)row * N + col], v);
                        else                  Cf[(size_t)row * N + col] += v;
                    } else if constexpr (EPI == 2) {
                        const float u = v + bias[col];
                        const float g = 0.5f * u * (1.0f + erff(u * 0.70710678118654752f));
                        Cb[(size_t)row * N + col] = (bf16)g;
                    } else if constexpr (EPI == 3) {
                        const float add = (SK == 1 || kz == 0) ? v + bias[col] : v;
                        if constexpr (SK > 1) atomicAdd(&Cf[(size_t)row * N + col], add);
                        else                  Cf[(size_t)row * N + col] += add;
                    } else if constexpr (EPI == 4) {
                        Cf[(size_t)row * N + col] = v + bias[col];
                    }
                }
            }
        }
    }
}

// ---------------------------------------------------------------------------
// 256x256 8-phase GEMM: Cf = A@Bt^T + bias. 8 waves (2Mx4N), BK=64.
// v2 fixes: sched_barrier pins ds_reads/stages above the raw s_barrier;
// explicit lgkmcnt(0) after it (m201 placement); tail-safe vmcnt (the
// round-5 version left A(t+1) loads unwaited at t=NT-2 — latent race).
// ---------------------------------------------------------------------------
__global__ __launch_bounds__(512, 2) void gemm256_bias_k(
    const bf16* __restrict__ A, const bf16* __restrict__ Bt,
    float* __restrict__ Cf, const float* __restrict__ bias,
    int M, int N, int K)
{
    __shared__ __align__(16) bf16 Al[2][256 * 64];
    __shared__ __align__(16) bf16 Bl[2][256 * 64];
    const int tid = threadIdx.x;
    const int l = tid & 63;
    const int wid = tid >> 6;            // 0..7
    const int wm = wid >> 2, wn = wid & 3;
    const int g = l >> 4, lc = l & 15;
    int bm = blockIdx.x, bn = blockIdx.y;
    xcd_remap(bm, bn, gridDim.x, gridDim.y);

    const bf16* Ab = A + (size_t)bm * 256 * K;
    const bf16* Bb = Bt + (size_t)bn * 256 * K;
    const int NT = K >> 6;

    f32x4 acc[8][4];
#pragma unroll
    for (int i = 0; i < 8; ++i)
#pragma unroll
        for (int j = 0; j < 4; ++j) acc[i][j] = (f32x4){0.f, 0.f, 0.f, 0.f};

    auto stageA = [&](int t, int mh) {
        bf16* dst = Al[t & 1] + mh * 8192;
#pragma unroll
        for (int ld = 0; ld < 2; ++ld) {
            const int c = ld * 512 + tid;           // 0..1023
            const int r = c >> 3, slot = c & 7;
            const int col = ((slot ^ (r & 7)) << 3);
            __builtin_amdgcn_global_load_lds(
                GL_AS(Ab + (size_t)(mh * 128 + r) * K + t * 64 + col),
                LDS_AS(dst + (ld * 512 + (tid & 448)) * 8), 16, 0, 0);
        }
    };
    auto stageB = [&](int t, int nh) {
        bf16* dst = Bl[t & 1] + nh * 8192;
#pragma unroll
        for (int ld = 0; ld < 2; ++ld) {
            const int c = ld * 512 + tid;
            const int r = c >> 3, slot = c & 7;
            const int col = ((slot ^ (r & 7)) << 3);
            __builtin_amdgcn_global_load_lds(
                GL_AS(Bb + (size_t)(nh * 128 + r) * K + t * 64 + col),
                LDS_AS(dst + (ld * 512 + (tid & 448)) * 8), 16, 0, 0);
        }
    };
    auto ldA = [&](bf16x8 (&a)[4][2], int mh, int p) {
#pragma unroll
        for (int i = 0; i < 4; ++i) {
            const int r = wm * 128 + mh * 64 + i * 16 + lc;
            const char* base = (const char*)Al[p] + r * 128;
#pragma unroll
            for (int ks = 0; ks < 2; ++ks)
                a[i][ks] = *(const bf16x8*)(base + ((ks * 64 + g * 16) ^ ((r & 7) << 4)));
        }
    };
    auto ldB = [&](bf16x8 (&b)[2][2], int nh, int p) {
#pragma unroll
        for (int i = 0; i < 2; ++i) {
            const int r = wn * 64 + nh * 32 + i * 16 + lc;
            const char* base = (const char*)Bl[p] + r * 128;
#pragma unroll
            for (int ks = 0; ks < 2; ++ks)
                b[i][ks] = *(const bf16x8*)(base + ((ks * 64 + g * 16) ^ ((r & 7) << 4)));
        }
    };
    auto mm = [&](bf16x8 (&a)[4][2], bf16x8 (&b)[2][2], int mh, int nh) {
        __builtin_amdgcn_s_setprio(1);
#pragma unroll
        for (int i = 0; i < 4; ++i)
#pragma unroll
            for (int jn = 0; jn < 2; ++jn) {
                f32x4 ac = acc[mh * 4 + i][nh * 2 + jn];
                ac = __builtin_amdgcn_mfma_f32_16x16x32_bf16(a[i][0], b[jn][0], ac, 0, 0, 0);
                ac = __builtin_amdgcn_mfma_f32_16x16x32_bf16(a[i][1], b[jn][1], ac, 0, 0, 0);
                acc[mh * 4 + i][nh * 2 + jn] = ac;
            }
        __builtin_amdgcn_s_setprio(0);
    };
    auto phase_sync = [&]() {
        __builtin_amdgcn_sched_barrier(0);          // pin ds_reads/stages above
        __builtin_amdgcn_s_barrier();
        asm volatile("s_waitcnt lgkmcnt(0)" ::: "memory");
        __builtin_amdgcn_sched_barrier(0);          // pin MFMAs below the wait
    };

    // prologue: tile0 fully + tile1's B halves; wait until tile0 landed
    stageB(0, 0); stageB(0, 1); stageA(0, 0); stageA(0, 1);
    if (NT > 1) { stageB(1, 0); stageB(1, 1); }
    asm volatile("s_waitcnt vmcnt(4)" ::: "memory");
    __builtin_amdgcn_s_barrier();

    for (int t = 0; t < NT; ++t) {
        const int p = t & 1;
        bf16x8 a[4][2], b0[2][2], b1[2][2];
        // ---- ph1: (mh0, nh0)
        ldA(a, 0, p); ldB(b0, 0, p);
        if (t + 1 < NT) stageA(t + 1, 0);
        phase_sync();
        mm(a, b0, 0, 0);
        __builtin_amdgcn_s_barrier();
        // ---- ph2: (mh0, nh1)
        ldB(b1, 1, p);
        if (t + 1 < NT) stageA(t + 1, 1);
        phase_sync();
        mm(a, b1, 0, 1);
        __builtin_amdgcn_s_barrier();
        // ---- ph3: (mh1, nh1)
        ldA(a, 1, p);
        if (t + 2 < NT) stageB(t + 2, 0);
        phase_sync();
        mm(a, b1, 1, 1);
        __builtin_amdgcn_s_barrier();
        // ---- ph4: (mh1, nh0); counted vmcnt in steady state, full drain at tail
        if (t + 2 < NT) stageB(t + 2, 1);
        __builtin_amdgcn_sched_barrier(0);
        if (t + 2 < NT) asm volatile("s_waitcnt vmcnt(4)" ::: "memory");
        else            asm volatile("s_waitcnt vmcnt(0)" ::: "memory");
        __builtin_amdgcn_s_barrier();
        asm volatile("s_waitcnt lgkmcnt(0)" ::: "memory");
        __builtin_amdgcn_sched_barrier(0);
        mm(a, b0, 1, 0);
        __builtin_amdgcn_s_barrier();
    }

    // ---- epilogue
    const int colb = bn * 256 + wn * 64;
    const int rowb = bm * 256 + wm * 128 + g * 4;
#pragma unroll
    for (int mi = 0; mi < 8; ++mi) {
#pragma unroll
        for (int ni = 0; ni < 4; ++ni) {
            const int col = colb + ni * 16 + lc;
#pragma unroll
            for (int j = 0; j < 4; ++j) {
                const int row = rowb + mi * 16 + j;
                Cf[(size_t)row * N + col] = acc[mi][ni][j] + bias[col];
            }
        }
    }
}

// ---------------------------------------------------------------------------
// MFMA flash attention v3. 4 waves/block, 64 q-rows/block (16/wave),
// KVBLK=64 (was 32): half the iterations/barriers/shfl-reduces, double the
// MFMA ILP. All waves process the same tiles; only the last tile is masked
// (per-row). K tile [64 keys][64 d], V tile [64 d][64 s], both 128B rows,
// XOR-swizzled 16B slots. Double-buffered, staged one tile ahead.
// ---------------------------------------------------------------------------
__global__ __launch_bounds__(256) void attn_mfma_k(
    const bf16* __restrict__ qkv, const bf16* __restrict__ vt,
    bf16* __restrict__ o)
{
    __shared__ __align__(16) bf16 Kl[2][64 * 64];
    __shared__ __align__(16) bf16 Vl[2][64 * 64];
    __shared__ __align__(16) bf16 Pl[4][16][136];  // hi cols 0..63, lo 72..135

    const int tid = threadIdx.x;
    const int w = tid >> 6, l = tid & 63;
    const int g = l >> 4, lc = l & 15;
    const int qt = blockIdx.x & 15;      // S/64 = 16 q-blocks
    const int bh = blockIdx.x >> 4;
    const int h = bh & 15, b = bh >> 4;
    const int q0 = qt * 64;
    const int qw = q0 + w * 16;          // this wave's q-subtile
    const int NT = qt + 1;               // 64-key tiles, last one masked

    const bf16* qbase = qkv + (size_t)b * 1024 * 3072 + h * 64;
    const bf16* kbase = qbase + 1024;
    const bf16* vbase = vt + (size_t)b * 128 * 8192 + h * 512;

    // Q A-frags: lane holds Q[qw+lc][dh*32 + g*8 + jj]
    bf16x8 af0, af1;
    {
        const bf16* qp = qbase + (size_t)(qw + lc) * 3072 + g * 8;
        af0 = *(const bf16x8*)qp;
        af1 = *(const bf16x8*)(qp + 32);
    }

    f32x4 acc[4];                        // O: rows qw+4g+j, cols dt*16+lc
#pragma unroll
    for (int dt = 0; dt < 4; ++dt) acc[dt] = (f32x4){0.f, 0.f, 0.f, 0.f};
    f32x4 m  = (f32x4){-1e30f, -1e30f, -1e30f, -1e30f};
    f32x4 ls = (f32x4){0.f, 0.f, 0.f, 0.f};

    // cooperative stage of 64-key tile t: 2 K-chunks + 2 V-chunks per thread
    auto stage = [&](int t) {
        const int k0 = t * 64;
        const int buf = t & 1;
#pragma unroll
        for (int ld = 0; ld < 2; ++ld) {
            const int c = ld * 256 + tid;
            const int row = c >> 3;                       // key 0..63
            const int d = (((c & 7) ^ (row & 7)) << 3);
            __builtin_amdgcn_global_load_lds(
                GL_AS(kbase + (size_t)(k0 + row) * 3072 + d),
                LDS_AS(Kl[buf] + (ld * 256 + (tid & 192)) * 8), 16, 0, 0);
        }
#pragma unroll
        for (int ld = 0; ld < 2; ++ld) {
            const int c = ld * 256 + tid;
            const int row = c >> 3;                       // d 0..63
            const int so = (c & 7) ^ (row & 7);           // s-octet
            __builtin_amdgcn_global_load_lds(
                GL_AS(vbase + (size_t)((k0 >> 3) + so) * 8192 + row * 8),
                LDS_AS(Vl[buf] + (ld * 256 + (tid & 192)) * 8), 16, 0, 0);
        }
    };

    auto compute = [&](int t, bool MASKED) {
        const char* KT = (const char*)Kl[t & 1];
        const char* VT = (const char*)Vl[t & 1];
        const int k0 = t * 64;

        // QK^T: 4 independent 2-chains over 4 key-subtiles
        f32x4 s[4];
#pragma unroll
        for (int kt = 0; kt < 4; ++kt) {
            const int r = kt * 16 + lc;
            const bf16x8 kf0 = *(const bf16x8*)(KT + r * 128 + ((g * 16)      ^ ((r & 7) << 4)));
            const bf16x8 kf1 = *(const bf16x8*)(KT + r * 128 + ((64 + g * 16) ^ ((r & 7) << 4)));
            f32x4 sv = (f32x4){0.f, 0.f, 0.f, 0.f};
            sv = __builtin_amdgcn_mfma_f32_16x16x32_bf16(af0, kf0, sv, 0, 0, 0);
            sv = __builtin_amdgcn_mfma_f32_16x16x32_bf16(af1, kf1, sv, 0, 0, 0);
            s[kt] = sv;
        }

        // scale (+ per-row causal mask on the last tile)
#pragma unroll
        for (int kt = 0; kt < 4; ++kt)
#pragma unroll
            for (int j = 0; j < 4; ++j) {
                if (MASKED) {
                    const int row = qw + 4 * g + j;
                    s[kt][j] = (k0 + kt * 16 + lc <= row) ? s[kt][j] * 0.125f : -1e30f;
                } else {
                    s[kt][j] *= 0.125f;
                }
            }

        // row-max: VALU over 4 subtiles, then one 4-level shfl over 16 lanes
        f32x4 tm;
#pragma unroll
        for (int j = 0; j < 4; ++j)
            tm[j] = fmaxf(fmaxf(s[0][j], s[1][j]), fmaxf(s[2][j], s[3][j]));
#pragma unroll
        for (int off = 8; off; off >>= 1)
#pragma unroll
            for (int j = 0; j < 4; ++j) tm[j] = fmaxf(tm[j], __shfl_xor(tm[j], off));

        f32x4 sc;
#pragma unroll
        for (int j = 0; j < 4; ++j) {
            const float mn = fmaxf(m[j], tm[j]);
            sc[j] = __expf(m[j] - mn);
            m[j] = mn;
        }
        f32x4 p[4];
#pragma unroll
        for (int kt = 0; kt < 4; ++kt)
#pragma unroll
            for (int j = 0; j < 4; ++j) p[kt][j] = __expf(s[kt][j] - m[j]);
#pragma unroll
        for (int j = 0; j < 4; ++j)
            ls[j] = ls[j] * sc[j] + ((p[0][j] + p[1][j]) + (p[2][j] + p[3][j]));
#pragma unroll
        for (int dt = 0; dt < 4; ++dt)
#pragma unroll
            for (int j = 0; j < 4; ++j) acc[dt][j] *= sc[j];

        // P -> LDS in C-layout; read back in A-frag layout. hi/lo bf16 split
        // keeps P at ~24-bit accuracy.
#pragma unroll
        for (int j = 0; j < 4; ++j) {
            const int r = 4 * g + j;
#pragma unroll
            for (int kt = 0; kt < 4; ++kt) {
                const bf16 hi = (bf16)p[kt][j];
                Pl[w][r][kt * 16 + lc]      = hi;
                Pl[w][r][72 + kt * 16 + lc] = (bf16)(p[kt][j] - (float)hi);
            }
        }
        bf16x8 pah[2], pal[2];
#pragma unroll
        for (int ks = 0; ks < 2; ++ks) {
            pah[ks] = *(const bf16x8*)&Pl[w][lc][ks * 32 + g * 8];
            pal[ks] = *(const bf16x8*)&Pl[w][lc][72 + ks * 32 + g * 8];
        }

        // PV: 4 independent 4-chains over output d-subtiles
#pragma unroll
        for (int dt = 0; dt < 4; ++dt) {
            const int r = dt * 16 + lc;
            const bf16x8 vf0 = *(const bf16x8*)(VT + r * 128 + ((g * 16)      ^ ((r & 7) << 4)));
            const bf16x8 vf1 = *(const bf16x8*)(VT + r * 128 + ((64 + g * 16) ^ ((r & 7) << 4)));
            f32x4 a = acc[dt];
            a = __builtin_amdgcn_mfma_f32_16x16x32_bf16(pah[0], vf0, a, 0, 0, 0);
            a = __builtin_amdgcn_mfma_f32_16x16x32_bf16(pah[1], vf1, a, 0, 0, 0);
            a = __builtin_amdgcn_mfma_f32_16x16x32_bf16(pal[0], vf0, a, 0, 0, 0);
            a = __builtin_amdgcn_mfma_f32_16x16x32_bf16(pal[1], vf1, a, 0, 0, 0);
            acc[dt] = a;
        }
    };

    stage(0);
    __syncthreads();                       // vmcnt drain: tile 0 visible
    for (int t = 0; t < NT; ++t) {
        if (t + 1 < NT) stage(t + 1);      // async into the other buffer
        compute(t, t == NT - 1);
        __syncthreads();                   // publish tile t+1; reads of t done
    }

    // reduce lane-partial row sums across the 16 cols, normalize, store
    f32x4 inv;
#pragma unroll
    for (int j = 0; j < 4; ++j) {
        float s = ls[j];
#pragma unroll
        for (int off = 8; off; off >>= 1) s += __shfl_xor(s, off);
        inv[j] = 1.0f / s;
    }
    bf16* op = o + (size_t)(b * 1024 + qw) * 1024 + h * 64;
#pragma unroll
    for (int dt = 0; dt < 4; ++dt)
#pragma unroll
        for (int j = 0; j < 4; ++j)
            op[(size_t)(4 * g + j) * 1024 + dt * 16 + lc] = (bf16)(acc[dt][j] * inv[j]);
}

// ---------------------------------------------------------------------------
extern "C" void kernel_launch(void* const* d_in, const int* in_sizes, int n_in,
                              void* d_out, int out_size, void* d_ws, size_t ws_size,
                              hipStream_t stream)
{
    const int B = 2, S = 1024, D = 1024, L = 6, F = 4096, V = 32000, H = 16;
    const int M = B * S;

    const int*   tokens    = (const int*)  d_in[0];
    const float* token_emb = (const float*)d_in[1];
    const float* Wqkv      = (const float*)d_in[2];
    const float* Wout      = (const float*)d_in[3];
    const float* ln1_s     = (const float*)d_in[4];
    const float* ln1_b     = (const float*)d_in[5];
    const float* W1        = (const float*)d_in[6];
    const float* b1        = (const float*)d_in[7];
    const float* W2        = (const float*)d_in[8];
    const float* b2        = (const float*)d_in[9];
    const float* ln2_s     = (const float*)d_in[10];
    const float* ln2_b     = (const float*)d_in[11];
    const float* lnf_s     = (const float*)d_in[12];
    const float* lnf_b     = (const float*)d_in[13];
    const float* Whead     = (const float*)d_in[14];
    const float* bhead     = (const float*)d_in[15];
    float* out = (float*)d_out;

    char* w = (char*)d_ws;
    size_t off = 0;
    auto alloc = [&](size_t n) { char* p = w + off; off += (n + 255) & ~(size_t)255; return p; };
    bf16* WqkvT  = (bf16*)alloc((size_t)L * 3 * D * D * 2);
    bf16* WoutT  = (bf16*)alloc((size_t)L * D * D * 2);
    bf16* W1T    = (bf16*)alloc((size_t)L * F * D * 2);
    bf16* W2T    = (bf16*)alloc((size_t)L * D * F * 2);
    bf16* WheadT = (bf16*)alloc((size_t)V * D * 2);
    float* x     = (float*)alloc((size_t)M * D * 4);
    bf16* h      = (bf16*)alloc((size_t)M * D * 2);
    bf16* qkv    = (bf16*)alloc((size_t)M * 3 * D * 2);
    bf16* ob     = (bf16*)alloc((size_t)M * D * 2);
    bf16* mid    = (bf16*)alloc((size_t)M * F * 2);
    bf16* vt     = mid;   // [b][s/8][1024 hd][8] = 4 MB, aliases mid

    TSeg s0{Wqkv,  WqkvT,  D, 3 * D, 3 * D / 32, (3 * D / 32) * (D / 32), (3 * D / 32) * (D / 32) * L};
    TSeg s1{Wout,  WoutT,  D, D,     D / 32,     (D / 32) * (D / 32),     (D / 32) * (D / 32) * L};
    TSeg s2{W1,    W1T,    D, F,     F / 32,     (F / 32) * (D / 32),     (F / 32) * (D / 32) * L};
    TSeg s3{W2,    W2T,    F, D,     D / 32,     (D / 32) * (F / 32),     (D / 32) * (F / 32) * L};
    TSeg s4{Whead, WheadT, D, V,     V / 32,     (V / 32) * (D / 32),     (V / 32) * (D / 32)};
    const int totTiles = s0.nTiles + s1.nTiles + s2.nTiles + s3.nTiles + s4.nTiles;
    transpose_all_k<<<totTiles, dim3(32, 8), 0, stream>>>(s0, s1, s2, s3, s4);

    embed_k<<<M, 256, 0, stream>>>(tokens, token_emb, x);

    for (int lyr = 0; lyr < L; ++lyr) {
        layernorm_k<<<M, 256, 0, stream>>>(x, ln1_s + lyr * D, ln1_b + lyr * D, h);
        gemm_bt_k<5><<<dim3(M / 128, 3 * D / 128), 256, 0, stream>>>(
            h, WqkvT + (size_t)lyr * 3 * D * D, nullptr, qkv, vt, nullptr, M, 3 * D, D);
        attn_mfma_k<<<B * H * S / 64, 256, 0, stream>>>(qkv, vt, ob);
        gemm_bt_k<1, 4><<<dim3(M / 128, D / 128, 4), 256, 0, stream>>>(
            ob, WoutT + (size_t)lyr * D * D, x, nullptr, nullptr, nullptr, M, D, D);
        layernorm_k<<<M, 256, 0, stream>>>(x, ln2_s + lyr * D, ln2_b + lyr * D, h);
        gemm_bt_k<2><<<dim3(M / 128, F / 128), 256, 0, stream>>>(
            h, W1T + (size_t)lyr * F * D, nullptr, mid, nullptr, b1 + lyr * F, M, F, D);
        gemm_bt_k<3, 4><<<dim3(M / 128, D / 128, 4), 256, 0, stream>>>(
            mid, W2T + (size_t)lyr * D * F, x, nullptr, nullptr, b2 + lyr * D, M, D, F);
    }
    layernorm_k<<<M, 256, 0, stream>>>(x, lnf_s, lnf_b, h);
    gemm256_bias_k<<<dim3(M / 256, V / 256), 512, 0, stream>>>(
        h, WheadT, out, bhead, M, V, D);
}

// Round 7
// 1445.330 us; speedup vs baseline: 1.1035x; 1.0455x over previous
//
#include <hip/hip_runtime.h>
#include <hip/hip_bf16.h>
#include <math.h>

typedef __bf16 bf16;
typedef __bf16 bf16x4 __attribute__((ext_vector_type(4)));
typedef __bf16 bf16x8 __attribute__((ext_vector_type(8)));
typedef float f32x4 __attribute__((ext_vector_type(4)));

#define GL_AS(p) ((const __attribute__((address_space(1))) void*)(p))
#define LDS_AS(p) ((__attribute__((address_space(3))) void*)(p))

// ---------------------------------------------------------------------------
// Bijective XCD-chunked remap (m204): hw round-robin -> contiguous chunk/XCD
// ---------------------------------------------------------------------------
__device__ inline void xcd_remap(int& bm, int& bn, int NBM, int NBN)
{
    const int nwg = NBM * NBN;
    const int flat = bm + NBM * bn;
    const int q = nwg >> 3, r = nwg & 7;
    const int x = flat & 7, i = flat >> 3;
    const int f2 = ((x < r) ? x * (q + 1) : r * (q + 1) + (x - r) * q) + i;
    bm = f2 % NBM;
    bn = f2 / NBM;
}

// ---------------------------------------------------------------------------
// Merged transpose + f32->bf16 cast for all 5 weight groups.
// ---------------------------------------------------------------------------
struct TSeg {
    const float* in; bf16* out; int R, C, nTilesC, tilesPerZ, nTiles;
};

__global__ __launch_bounds__(256) void transpose_all_k(
    TSeg s0, TSeg s1, TSeg s2, TSeg s3, TSeg s4)
{
    int t = blockIdx.x;
    TSeg s;
    if (t < s0.nTiles) s = s0;
    else { t -= s0.nTiles;
    if (t < s1.nTiles) s = s1;
    else { t -= s1.nTiles;
    if (t < s2.nTiles) s = s2;
    else { t -= s2.nTiles;
    if (t < s3.nTiles) s = s3;
    else { t -= s3.nTiles; s = s4; }}}}

    const int z   = t / s.tilesPerZ;
    const int rem = t - z * s.tilesPerZ;
    const int cx  = rem % s.nTilesC, ry = rem / s.nTilesC;

    __shared__ float tl[32][33];
    const int c0 = cx * 32, r0 = ry * 32;
    const size_t zoff = (size_t)z * s.R * s.C;
    const float* inb = s.in + zoff;
    bf16* outb = s.out + zoff;
    const int tx = threadIdx.x, ty = threadIdx.y;   // (32, 8)
#pragma unroll
    for (int i = 0; i < 32; i += 8)
        tl[ty + i][tx] = inb[(size_t)(r0 + ty + i) * s.C + c0 + tx];
    __syncthreads();
#pragma unroll
    for (int i = 0; i < 32; i += 8)
        outb[(size_t)(c0 + ty + i) * s.R + r0 + tx] = (bf16)tl[tx][ty + i];
}

// ---------------------------------------------------------------------------
// Embedding + sinusoidal positional encoding -> x f32 [B*S, 1024]
// ---------------------------------------------------------------------------
__global__ __launch_bounds__(256) void embed_k(
    const int* __restrict__ tok, const float* __restrict__ emb,
    float* __restrict__ x)
{
    const int D = 1024;
    const int row = blockIdx.x;
    const int s = row & 1023;          // S = 1024
    const int t = tok[row];
    const int d0 = threadIdx.x * 4;
    const float c = 9.210340371976184f / 512.0f;
    const float div0 = expf(-(float)(d0 >> 1) * c);
    const float div1 = expf(-(float)((d0 >> 1) + 1) * c);
    const float a0 = (float)s * div0, a1 = (float)s * div1;
    const f32x4 e = *(const f32x4*)(emb + (size_t)t * D + d0);
    f32x4 o;
    o[0] = e[0] + sinf(a0);
    o[1] = e[1] + cosf(a0);
    o[2] = e[2] + sinf(a1);
    o[3] = e[3] + cosf(a1);
    *(f32x4*)(x + (size_t)row * D + d0) = o;
}

// ---------------------------------------------------------------------------
// LayerNorm (D=1024): x f32 -> out bf16, vectorized 4 elems/thread
// ---------------------------------------------------------------------------
__global__ __launch_bounds__(256) void layernorm_k(
    const float* __restrict__ x, const float* __restrict__ sc,
    const float* __restrict__ bi, bf16* __restrict__ out)
{
    const int D = 1024;
    const int row = blockIdx.x;
    const int d0 = threadIdx.x * 4;
    const f32x4 v = *(const f32x4*)(x + (size_t)row * D + d0);
    float s = v[0] + v[1] + v[2] + v[3];
    float q = v[0] * v[0] + v[1] * v[1] + v[2] * v[2] + v[3] * v[3];
#pragma unroll
    for (int o = 32; o; o >>= 1) { s += __shfl_xor(s, o); q += __shfl_xor(q, o); }
    __shared__ float ls[4], lq[4];
    const int w = threadIdx.x >> 6;
    if ((threadIdx.x & 63) == 0) { ls[w] = s; lq[w] = q; }
    __syncthreads();
    const float S = ls[0] + ls[1] + ls[2] + ls[3];
    const float Q = lq[0] + lq[1] + lq[2] + lq[3];
    const float mu = S * (1.0f / D);
    const float var = Q * (1.0f / D) - mu * mu;
    const float rstd = rsqrtf(var + 1e-5f);
    const f32x4 sc4 = *(const f32x4*)(sc + d0);
    const f32x4 bi4 = *(const f32x4*)(bi + d0);
    bf16x4 o4;
#pragma unroll
    for (int i = 0; i < 4; ++i) o4[i] = (bf16)((v[i] - mu) * rstd * sc4[i] + bi4[i]);
    *(bf16x4*)(out + (size_t)row * D + d0) = o4;
}

// ---------------------------------------------------------------------------
// GEMM: C[M,N] = A[M,K](bf16) @ Bt[N,K](bf16)^T, f32 accum, various epilogues
// 128x128 tile, BK=64, 4 waves (2x2), mfma_f32_16x16x32_bf16
// EPI: 0 store bf16 | 1 Cf += acc (atomic if SK>1) | 2 bias+gelu->bf16
//      3 Cf += acc+bias (atomic if SK>1) | 4 Cf = acc+bias
//      5 qkv write: cols<2048 -> Cb, cols>=2048 -> Cb2 = vt[b][s/8][hd][8]
// SK: split-K factor. SWZ: XCD-chunked block remap (off for the head; A/B
// evidence r2 vs r4: head 166 no-swz vs 173 swz).
// ---------------------------------------------------------------------------
template <int EPI, int SK = 1, bool SWZ = true>
__global__ __launch_bounds__(256, 2) void gemm_bt_k(
    const bf16* __restrict__ A, const bf16* __restrict__ Bt,
    float* __restrict__ Cf, bf16* __restrict__ Cb, bf16* __restrict__ Cb2,
    const float* __restrict__ bias, int M, int N, int K)
{
    __shared__ __align__(16) bf16 Al[128 * 64];
    __shared__ __align__(16) bf16 Bl[128 * 64];
    const int tid = threadIdx.x;
    const int l = tid & 63;
    const int wbase = tid & 192;                 // wave_id * 64
    const int wr = (tid >> 7) & 1, wc = (tid >> 6) & 1;
    int bm = blockIdx.x, bn = blockIdx.y;
    if constexpr (SWZ) xcd_remap(bm, bn, gridDim.x, gridDim.y);
    const int kz = blockIdx.z;
    const int Kc = K / SK;                       // this slice's K extent

    f32x4 acc[4][4];
#pragma unroll
    for (int i = 0; i < 4; ++i)
#pragma unroll
        for (int j = 0; j < 4; ++j) acc[i][j] = (f32x4){0.f, 0.f, 0.f, 0.f};

    const bf16* Abase = A + (size_t)bm * 128 * K + (size_t)kz * Kc;
    const bf16* Bbase = Bt + (size_t)bn * 128 * K + (size_t)kz * Kc;

    for (int k0 = 0; k0 < Kc; k0 += 64) {
#pragma unroll
        for (int i = 0; i < 4; ++i) {
            const int c = i * 256 + tid;
            const int row = c >> 3, slot = c & 7;
            const int col = ((slot ^ (row & 7)) << 3);
            __builtin_amdgcn_global_load_lds(
                GL_AS(Abase + (size_t)row * K + k0 + col),
                LDS_AS(Al + (i * 256 + wbase) * 8), 16, 0, 0);
        }
#pragma unroll
        for (int i = 0; i < 4; ++i) {
            const int c = i * 256 + tid;
            const int row = c >> 3, slot = c & 7;
            const int col = ((slot ^ (row & 7)) << 3);
            __builtin_amdgcn_global_load_lds(
                GL_AS(Bbase + (size_t)row * K + k0 + col),
                LDS_AS(Bl + (i * 256 + wbase) * 8), 16, 0, 0);
        }
        __syncthreads();   // drains vmcnt: tiles visible

#pragma unroll
        for (int ks = 0; ks < 2; ++ks) {
            bf16x8 af[4], bfr[4];
            const int kb = ks * 64 + ((l >> 4) << 4);
#pragma unroll
            for (int mi = 0; mi < 4; ++mi) {
                const int r = wr * 64 + mi * 16 + (l & 15);
                af[mi] = *(const bf16x8*)((const char*)Al + r * 128 + (kb ^ ((r & 7) << 4)));
            }
#pragma unroll
            for (int ni = 0; ni < 4; ++ni) {
                const int r = wc * 64 + ni * 16 + (l & 15);
                bfr[ni] = *(const bf16x8*)((const char*)Bl + r * 128 + (kb ^ ((r & 7) << 4)));
            }
#pragma unroll
            for (int mi = 0; mi < 4; ++mi)
#pragma unroll
                for (int ni = 0; ni < 4; ++ni)
                    acc[mi][ni] = __builtin_amdgcn_mfma_f32_16x16x32_bf16(
                        af[mi], bfr[ni], acc[mi][ni], 0, 0, 0);
        }
        __syncthreads();
    }

    // ---- epilogue: C/D layout col=lane&15, row=(lane>>4)*4+j  [m89/m91]
    const int colb = bn * 128 + wc * 64;
    const int rowb = bm * 128 + wr * 64 + ((l >> 4) << 2);
#pragma unroll
    for (int mi = 0; mi < 4; ++mi) {
#pragma unroll
        for (int ni = 0; ni < 4; ++ni) {
            const int col = colb + ni * 16 + (l & 15);
            if constexpr (EPI == 5) {
                const int row0 = rowb + mi * 16;
                if (col < 2048) {
#pragma unroll
                    for (int j = 0; j < 4; ++j)
                        Cb[(size_t)(row0 + j) * N + col] = (bf16)acc[mi][ni][j];
                } else {
                    bf16x4 v4;
#pragma unroll
                    for (int j = 0; j < 4; ++j) v4[j] = (bf16)acc[mi][ni][j];
                    *(bf16x4*)&Cb2[((size_t)(row0 >> 3) * 1024 + (col - 2048)) * 8 + (row0 & 7)] = v4;
                }
            } else {
#pragma unroll
                for (int j = 0; j < 4; ++j) {
                    const int row = rowb + mi * 16 + j;
                    const float v = acc[mi][ni][j];
                    if constexpr (EPI == 0) {
                        Cb[(size_t)row * N + col] = (bf16)v;
                    } else if constexpr (EPI == 1) {
                        if constexpr (SK > 1) atomicAdd(&Cf[(size_t)row * N + col], v);
                        else                  Cf[(size_t)row * N + col] += v;
                    } else if constexpr (EPI == 2) {
                        const float u = v + bias[col];
                        const float g = 0.5f * u * (1.0f + erff(u * 0.70710678118654752f));
                        Cb[(size_t)row * N + col] = (bf16)g;
                    } else if constexpr (EPI == 3) {
                        const float add = (SK == 1 || kz == 0) ? v + bias[col] : v;
                        if constexpr (SK > 1) atomicAdd(&Cf[(size_t)row * N + col], add);
                        else                  Cf[(size_t)row * N + col] += add;
                    } else if constexpr (EPI == 4) {
                        Cf[(size_t)row * N + col] = v + bias[col];
                    }
                }
            }
        }
    }
}

// ---------------------------------------------------------------------------
// MFMA flash attention v3.1. 4 waves/block, 64 q-rows/block (16/wave),
// KVBLK=64. Load-balance fix: work per block is NT = qt+1 tiles (1..16);
// with 512 blocks, blocks i and i+256 land on the same CU under round-robin
// and (i & 15) == ((i+256) & 15) gave both the SAME qt -> heaviest CUs did
// 32 tiles. Complement remap (bh>=16 takes qt=15-qt) makes every such pair
// sum to 17 tiles. Pure bijection, no math change.
// ---------------------------------------------------------------------------
__global__ __launch_bounds__(256) void attn_mfma_k(
    const bf16* __restrict__ qkv, const bf16* __restrict__ vt,
    bf16* __restrict__ o)
{
    __shared__ __align__(16) bf16 Kl[2][64 * 64];
    __shared__ __align__(16) bf16 Vl[2][64 * 64];
    __shared__ __align__(16) bf16 Pl[4][16][136];  // hi cols 0..63, lo 72..135

    const int tid = threadIdx.x;
    const int w = tid >> 6, l = tid & 63;
    const int g = l >> 4, lc = l & 15;
    const int bh = blockIdx.x >> 4;      // 0..31 = b*16 + h
    int qt = blockIdx.x & 15;            // S/64 = 16 q-blocks
    if (bh & 16) qt = 15 - qt;           // complement pairing (load balance)
    const int h = bh & 15, b = bh >> 4;
    const int q0 = qt * 64;
    const int qw = q0 + w * 16;          // this wave's q-subtile
    const int NT = qt + 1;               // 64-key tiles, last one masked

    const bf16* qbase = qkv + (size_t)b * 1024 * 3072 + h * 64;
    const bf16* kbase = qbase + 1024;
    const bf16* vbase = vt + (size_t)b * 128 * 8192 + h * 512;

    // Q A-frags: lane holds Q[qw+lc][dh*32 + g*8 + jj]
    bf16x8 af0, af1;
    {
        const bf16* qp = qbase + (size_t)(qw + lc) * 3072 + g * 8;
        af0 = *(const bf16x8*)qp;
        af1 = *(const bf16x8*)(qp + 32);
    }

    f32x4 acc[4];                        // O: rows qw+4g+j, cols dt*16+lc
#pragma unroll
    for (int dt = 0; dt < 4; ++dt) acc[dt] = (f32x4){0.f, 0.f, 0.f, 0.f};
    f32x4 m  = (f32x4){-1e30f, -1e30f, -1e30f, -1e30f};
    f32x4 ls = (f32x4){0.f, 0.f, 0.f, 0.f};

    // cooperative stage of 64-key tile t: 2 K-chunks + 2 V-chunks per thread
    auto stage = [&](int t) {
        const int k0 = t * 64;
        const int buf = t & 1;
#pragma unroll
        for (int ld = 0; ld < 2; ++ld) {
            const int c = ld * 256 + tid;
            const int row = c >> 3;                       // key 0..63
            const int d = (((c & 7) ^ (row & 7)) << 3);
            __builtin_amdgcn_global_load_lds(
                GL_AS(kbase + (size_t)(k0 + row) * 3072 + d),
                LDS_AS(Kl[buf] + (ld * 256 + (tid & 192)) * 8), 16, 0, 0);
        }
#pragma unroll
        for (int ld = 0; ld < 2; ++ld) {
            const int c = ld * 256 + tid;
            const int row = c >> 3;                       // d 0..63
            const int so = (c & 7) ^ (row & 7);           // s-octet
            __builtin_amdgcn_global_load_lds(
                GL_AS(vbase + (size_t)((k0 >> 3) + so) * 8192 + row * 8),
                LDS_AS(Vl[buf] + (ld * 256 + (tid & 192)) * 8), 16, 0, 0);
        }
    };

    auto compute = [&](int t, bool MASKED) {
        const char* KT = (const char*)Kl[t & 1];
        const char* VT = (const char*)Vl[t & 1];
        const int k0 = t * 64;

        // QK^T: 4 independent 2-chains over 4 key-subtiles
        f32x4 s[4];
#pragma unroll
        for (int kt = 0; kt < 4; ++kt) {
            const int r = kt * 16 + lc;
            const bf16x8 kf0 = *(const bf16x8*)(KT + r * 128 + ((g * 16)      ^ ((r & 7) << 4)));
            const bf16x8 kf1 = *(const bf16x8*)(KT + r * 128 + ((64 + g * 16) ^ ((r & 7) << 4)));
            f32x4 sv = (f32x4){0.f, 0.f, 0.f, 0.f};
            sv = __builtin_amdgcn_mfma_f32_16x16x32_bf16(af0, kf0, sv, 0, 0, 0);
            sv = __builtin_amdgcn_mfma_f32_16x16x32_bf16(af1, kf1, sv, 0, 0, 0);
            s[kt] = sv;
        }

        // scale (+ per-row causal mask on the last tile)
#pragma unroll
        for (int kt = 0; kt < 4; ++kt)
#pragma unroll
            for (int j = 0; j < 4; ++j) {
                if (MASKED) {
                    const int row = qw + 4 * g + j;
                    s[kt][j] = (k0 + kt * 16 + lc <= row) ? s[kt][j] * 0.125f : -1e30f;
                } else {
                    s[kt][j] *= 0.125f;
                }
            }

        // row-max: VALU over 4 subtiles, then one 4-level shfl over 16 lanes
        f32x4 tm;
#pragma unroll
        for (int j = 0; j < 4; ++j)
            tm[j] = fmaxf(fmaxf(s[0][j], s[1][j]), fmaxf(s[2][j], s[3][j]));
#pragma unroll
        for (int off = 8; off; off >>= 1)
#pragma unroll
            for (int j = 0; j < 4; ++j) tm[j] = fmaxf(tm[j], __shfl_xor(tm[j], off));

        f32x4 sc;
#pragma unroll
        for (int j = 0; j < 4; ++j) {
            const float mn = fmaxf(m[j], tm[j]);
            sc[j] = __expf(m[j] - mn);
            m[j] = mn;
        }
        f32x4 p[4];
#pragma unroll
        for (int kt = 0; kt < 4; ++kt)
#pragma unroll
            for (int j = 0; j < 4; ++j) p[kt][j] = __expf(s[kt][j] - m[j]);
#pragma unroll
        for (int j = 0; j < 4; ++j)
            ls[j] = ls[j] * sc[j] + ((p[0][j] + p[1][j]) + (p[2][j] + p[3][j]));
#pragma unroll
        for (int dt = 0; dt < 4; ++dt)
#pragma unroll
            for (int j = 0; j < 4; ++j) acc[dt][j] *= sc[j];

        // P -> LDS in C-layout; read back in A-frag layout. hi/lo bf16 split
        // keeps P at ~24-bit accuracy.
#pragma unroll
        for (int j = 0; j < 4; ++j) {
            const int r = 4 * g + j;
#pragma unroll
            for (int kt = 0; kt < 4; ++kt) {
                const bf16 hi = (bf16)p[kt][j];
                Pl[w][r][kt * 16 + lc]      = hi;
                Pl[w][r][72 + kt * 16 + lc] = (bf16)(p[kt][j] - (float)hi);
            }
        }
        bf16x8 pah[2], pal[2];
#pragma unroll
        for (int ks = 0; ks < 2; ++ks) {
            pah[ks] = *(const bf16x8*)&Pl[w][lc][ks * 32 + g * 8];
            pal[ks] = *(const bf16x8*)&Pl[w][lc][72 + ks * 32 + g * 8];
        }

        // PV: 4 independent 4-chains over output d-subtiles
#pragma unroll
        for (int dt = 0; dt < 4; ++dt) {
            const int r = dt * 16 + lc;
            const bf16x8 vf0 = *(const bf16x8*)(VT + r * 128 + ((g * 16)      ^ ((r & 7) << 4)));
            const bf16x8 vf1 = *(const bf16x8*)(VT + r * 128 + ((64 + g * 16) ^ ((r & 7) << 4)));
            f32x4 a = acc[dt];
            a = __builtin_amdgcn_mfma_f32_16x16x32_bf16(pah[0], vf0, a, 0, 0, 0);
            a = __builtin_amdgcn_mfma_f32_16x16x32_bf16(pah[1], vf1, a, 0, 0, 0);
            a = __builtin_amdgcn_mfma_f32_16x16x32_bf16(pal[0], vf0, a, 0, 0, 0);
            a = __builtin_amdgcn_mfma_f32_16x16x32_bf16(pal[1], vf1, a, 0, 0, 0);
            acc[dt] = a;
        }
    };

    stage(0);
    __syncthreads();                       // vmcnt drain: tile 0 visible
    for (int t = 0; t < NT; ++t) {
        if (t + 1 < NT) stage(t + 1);      // async into the other buffer
        compute(t, t == NT - 1);
        __syncthreads();                   // publish tile t+1; reads of t done
    }

    // reduce lane-partial row sums across the 16 cols, normalize, store
    f32x4 inv;
#pragma unroll
    for (int j = 0; j < 4; ++j) {
        float s = ls[j];
#pragma unroll
        for (int off = 8; off; off >>= 1) s += __shfl_xor(s, off);
        inv[j] = 1.0f / s;
    }
    bf16* op = o + (size_t)(b * 1024 + qw) * 1024 + h * 64;
#pragma unroll
    for (int dt = 0; dt < 4; ++dt)
#pragma unroll
        for (int j = 0; j < 4; ++j)
            op[(size_t)(4 * g + j) * 1024 + dt * 16 + lc] = (bf16)(acc[dt][j] * inv[j]);
}

// ---------------------------------------------------------------------------
extern "C" void kernel_launch(void* const* d_in, const int* in_sizes, int n_in,
                              void* d_out, int out_size, void* d_ws, size_t ws_size,
                              hipStream_t stream)
{
    const int B = 2, S = 1024, D = 1024, L = 6, F = 4096, V = 32000, H = 16;
    const int M = B * S;

    const int*   tokens    = (const int*)  d_in[0];
    const float* token_emb = (const float*)d_in[1];
    const float* Wqkv      = (const float*)d_in[2];
    const float* Wout      = (const float*)d_in[3];
    const float* ln1_s     = (const float*)d_in[4];
    const float* ln1_b     = (const float*)d_in[5];
    const float* W1        = (const float*)d_in[6];
    const float* b1        = (const float*)d_in[7];
    const float* W2        = (const float*)d_in[8];
    const float* b2        = (const float*)d_in[9];
    const float* ln2_s     = (const float*)d_in[10];
    const float* ln2_b     = (const float*)d_in[11];
    const float* lnf_s     = (const float*)d_in[12];
    const float* lnf_b     = (const float*)d_in[13];
    const float* Whead     = (const float*)d_in[14];
    const float* bhead     = (const float*)d_in[15];
    float* out = (float*)d_out;

    char* w = (char*)d_ws;
    size_t off = 0;
    auto alloc = [&](size_t n) { char* p = w + off; off += (n + 255) & ~(size_t)255; return p; };
    bf16* WqkvT  = (bf16*)alloc((size_t)L * 3 * D * D * 2);
    bf16* WoutT  = (bf16*)alloc((size_t)L * D * D * 2);
    bf16* W1T    = (bf16*)alloc((size_t)L * F * D * 2);
    bf16* W2T    = (bf16*)alloc((size_t)L * D * F * 2);
    bf16* WheadT = (bf16*)alloc((size_t)V * D * 2);
    float* x     = (float*)alloc((size_t)M * D * 4);
    bf16* h      = (bf16*)alloc((size_t)M * D * 2);
    bf16* qkv    = (bf16*)alloc((size_t)M * 3 * D * 2);
    bf16* ob     = (bf16*)alloc((size_t)M * D * 2);
    bf16* mid    = (bf16*)alloc((size_t)M * F * 2);
    bf16* vt     = mid;   // [b][s/8][1024 hd][8] = 4 MB, aliases mid

    TSeg s0{Wqkv,  WqkvT,  D, 3 * D, 3 * D / 32, (3 * D / 32) * (D / 32), (3 * D / 32) * (D / 32) * L};
    TSeg s1{Wout,  WoutT,  D, D,     D / 32,     (D / 32) * (D / 32),     (D / 32) * (D / 32) * L};
    TSeg s2{W1,    W1T,    D, F,     F / 32,     (F / 32) * (D / 32),     (F / 32) * (D / 32) * L};
    TSeg s3{W2,    W2T,    F, D,     D / 32,     (D / 32) * (F / 32),     (D / 32) * (F / 32) * L};
    TSeg s4{Whead, WheadT, D, V,     V / 32,     (V / 32) * (D / 32),     (V / 32) * (D / 32)};
    const int totTiles = s0.nTiles + s1.nTiles + s2.nTiles + s3.nTiles + s4.nTiles;
    transpose_all_k<<<totTiles, dim3(32, 8), 0, stream>>>(s0, s1, s2, s3, s4);

    embed_k<<<M, 256, 0, stream>>>(tokens, token_emb, x);

    for (int lyr = 0; lyr < L; ++lyr) {
        layernorm_k<<<M, 256, 0, stream>>>(x, ln1_s + lyr * D, ln1_b + lyr * D, h);
        gemm_bt_k<5><<<dim3(M / 128, 3 * D / 128), 256, 0, stream>>>(
            h, WqkvT + (size_t)lyr * 3 * D * D, nullptr, qkv, vt, nullptr, M, 3 * D, D);
        attn_mfma_k<<<B * H * S / 64, 256, 0, stream>>>(qkv, vt, ob);
        gemm_bt_k<1, 2><<<dim3(M / 128, D / 128, 2), 256, 0, stream>>>(
            ob, WoutT + (size_t)lyr * D * D, x, nullptr, nullptr, nullptr, M, D, D);
        layernorm_k<<<M, 256, 0, stream>>>(x, ln2_s + lyr * D, ln2_b + lyr * D, h);
        gemm_bt_k<2><<<dim3(M / 128, F / 128), 256, 0, stream>>>(
            h, W1T + (size_t)lyr * F * D, nullptr, mid, nullptr, b1 + lyr * F, M, F, D);
        gemm_bt_k<3, 2><<<dim3(M / 128, D / 128, 2), 256, 0, stream>>>(
            mid, W2T + (size_t)lyr * D * F, x, nullptr, nullptr, b2 + lyr * D, M, D, F);
    }
    layernorm_k<<<M, 256, 0, stream>>>(x, lnf_s, lnf_b, h);
    // head: proven-best 128x128 variant, no XCD remap (r2: 166 us)
    gemm_bt_k<4, 1, false><<<dim3(M / 128, V / 128), 256, 0, stream>>>(
        h, WheadT, out, nullptr, nullptr, bhead, M, V, D);
}